// Round 3
// baseline (189.060 us; speedup 1.0000x reference)
//
#include <hip/hip_runtime.h>
#include <math.h>

// GeoAttention on gfx950: B=2, S=2048, DIM=512, H=8, HD=64.
// bf16 MFMA (16x16x32) everywhere, fp32 accumulate.
// R11 = R10 resubmitted (R10 bench was an infra failure: "container failed
// twice", no counters). qkv_mfma re-tiled for occupancy — the R9 128x128
// tile gave only 384 blocks (1.5/CU), exposing the per-K-step
// vmcnt(0)+barrier drain (MfmaUtil 8%). Now 128 rows x 64 cols per block,
// 2 waves (each 64x64 = one head), grid (24,32) = 768 blocks -> 3 blocks/CU
// resident; drains overlap across blocks. Wave-level MFMA density unchanged
// (16 MFMA / 8KB LDS reads). out_mfma/attn_mfma unchanged from R9.

typedef __attribute__((ext_vector_type(8))) short short8;
typedef __attribute__((ext_vector_type(4))) short bf16x4;
typedef __attribute__((ext_vector_type(4))) float f32x4;

#define MFMA(a, b, c) __builtin_amdgcn_mfma_f32_16x16x32_bf16((a), (b), (c), 0, 0, 0)

static __device__ __forceinline__ short f2bf(float f) {
    unsigned u = __float_as_uint(f);
    u += 0x7fffu + ((u >> 16) & 1u);          // round-to-nearest-even
    return (short)(u >> 16);
}

// global -> LDS direct DMA, 16B per lane, wave-uniform LDS base + lane*16
static __device__ __forceinline__ void gld_lds16(const short* g, short* l) {
    __builtin_amdgcn_global_load_lds(
        (const __attribute__((address_space(1))) unsigned int*)g,
        (__attribute__((address_space(3))) unsigned int*)l, 16, 0, 0);
}

// ---------------------------------------------------------------------------
// Prep 1: xb[4096][1024] bf16 = concat(x_real, x_imag)
// ---------------------------------------------------------------------------
__global__ __launch_bounds__(256) void convert_x(
    const float* __restrict__ xr, const float* __restrict__ xi,
    short* __restrict__ xb)
{
    int idx = blockIdx.x * 256 + threadIdx.x;
    int e = idx << 2;
    int m = e >> 10, k = e & 1023;
    const float* src = (k < 512) ? xr : xi;
    float4 t = *(const float4*)(src + (size_t)m * 512 + (k & 511));
    unsigned lo = (unsigned short)f2bf(t.x) | ((unsigned)(unsigned short)f2bf(t.y) << 16);
    unsigned hi = (unsigned short)f2bf(t.z) | ((unsigned)(unsigned short)f2bf(t.w) << 16);
    uint2 o; o.x = lo; o.y = hi;
    *(uint2*)(xb + e) = o;
}

// ---------------------------------------------------------------------------
// Prep 2: transpose + convert weights to bf16, n-major [N][K].
// wqt/wkt/wvt are contiguous in the workspace => single wcat[1536][1024].
// ---------------------------------------------------------------------------
__global__ __launch_bounds__(256) void transpose_w(
    const float* __restrict__ Wq, const float* __restrict__ Wk,
    const float* __restrict__ Wv, const float* __restrict__ Wo,
    short* __restrict__ wqt, short* __restrict__ wkt,
    short* __restrict__ wvt, short* __restrict__ wot)
{
    __shared__ float t[32][33];
    const int z = blockIdx.z;
    const float* src = (z == 0) ? Wq : (z == 1) ? Wk : (z == 2) ? Wv : Wo;
    short* dst = (z == 0) ? wqt : (z == 1) ? wkt : (z == 2) ? wvt : wot;
    const int K = (z < 3) ? 1024 : 512;
    const int N = (z < 3) ? 512 : 1024;
    const int n0 = blockIdx.x << 5, k0 = blockIdx.y << 5;
    if (n0 >= N || k0 >= K) return;
    const int tx = threadIdx.x & 31, ty = threadIdx.x >> 5;
    #pragma unroll
    for (int i = 0; i < 4; ++i)
        t[ty + 8 * i][tx] = src[(size_t)(k0 + ty + 8 * i) * N + n0 + tx];
    __syncthreads();
    #pragma unroll
    for (int i = 0; i < 4; ++i)
        dst[(size_t)(n0 + ty + 8 * i) * K + k0 + tx] = f2bf(t[tx][ty + 8 * i]);
}

// ---------------------------------------------------------------------------
// Kernel 1: QKV projection. Grid (24, 32), 128 threads = 2 waves.
// Block tile = 128 rows x 64 cols over K=1024 (BK=32, 32 steps).
// jb: op = jb>>3 (0=Q,1=K,2=V), h = jb&7. Wave w owns rows [m0+w*64, +64)
// of head h => fused softmax(64)+sqrt epilogue per wave, unchanged.
// ---------------------------------------------------------------------------
__global__ __launch_bounds__(128, 4) void qkv_mfma(
    const short* __restrict__ xb, const short* __restrict__ wcat,
    const float* __restrict__ bq, const float* __restrict__ bk,
    const float* __restrict__ bv,
    short* __restrict__ sp, short* __restrict__ sq, short* __restrict__ vt)
{
    __shared__ short As[2][128 * 32];     // [row][k] 8KB per buffer
    __shared__ short Bs[2][64 * 32];      // [col][k] 4KB per buffer
    const int jb = blockIdx.x;            // 0..23
    const int m0 = blockIdx.y << 7;       // 128-row tile
    const int tid = threadIdx.x;
    const int w = tid >> 6, lane = tid & 63;
    const int l = lane & 15, quad = lane >> 4;

    // staging: 1KB chunk = 16 rows x 64B; lane -> row (lane>>2), seg (lane&3)*8
    // wave w stages A-chunks {4w..4w+3}, B-chunks {2w, 2w+1}
    const int srow = lane >> 2;
    const int sseg = (lane & 3) << 3;
    const short* gA = xb   + (size_t)(m0        + (w << 6) + srow) * 1024 + sseg;
    const short* gB = wcat + (size_t)((jb << 6) + (w << 5) + srow) * 1024 + sseg;

    // prologue: k-tile 0 -> buffer 0
    #pragma unroll
    for (int t = 0; t < 4; ++t)
        gld_lds16(gA + t * 16 * 1024, &As[0][((w << 2) + t) << 9]);
    #pragma unroll
    for (int t = 0; t < 2; ++t)
        gld_lds16(gB + t * 16 * 1024, &Bs[0][((w << 1) + t) << 9]);
    __syncthreads();

    const f32x4 z4 = {0.f, 0.f, 0.f, 0.f};
    f32x4 acc[4][4];
    #pragma unroll
    for (int i = 0; i < 4; ++i)
        #pragma unroll
        for (int j = 0; j < 4; ++j) acc[i][j] = z4;

    for (int kt = 0; kt < 32; ++kt) {
        const int cb = kt & 1, nb = cb ^ 1;
        if (kt < 31) {
            const int k0 = (kt + 1) << 5;
            #pragma unroll
            for (int t = 0; t < 4; ++t)
                gld_lds16(gA + k0 + t * 16 * 1024, &As[nb][((w << 2) + t) << 9]);
            #pragma unroll
            for (int t = 0; t < 2; ++t)
                gld_lds16(gB + k0 + t * 16 * 1024, &Bs[nb][((w << 1) + t) << 9]);
        }
        const short* Al = &As[cb][(w << 6) << 5];   // wave rows: w*64
        const short* Bl = &Bs[cb][0];
        short8 af[4], bfr[4];
        #pragma unroll
        for (int i = 0; i < 4; ++i)
            af[i] = *(const short8*)(Al + (((i << 4) + l) << 5) + (quad << 3));
        #pragma unroll
        for (int j = 0; j < 4; ++j)
            bfr[j] = *(const short8*)(Bl + (((j << 4) + l) << 5) + (quad << 3));
        #pragma unroll
        for (int i = 0; i < 4; ++i)
            #pragma unroll
            for (int j = 0; j < 4; ++j)
                acc[i][j] = MFMA(af[i], bfr[j], acc[i][j]);
        __syncthreads();
    }

    const int op = jb >> 3;               // 0=Q 1=K 2=V
    const int h  = jb & 7;                // head for this block

    if (op < 2) {
        short* dst = (op == 0) ? sp : sq;
        const float* bias = (op == 0) ? bq : bk;
        float bcol[4];
        #pragma unroll
        for (int nt = 0; nt < 4; ++nt) bcol[nt] = bias[(h << 6) + (nt << 4) + l];
        #pragma unroll
        for (int i = 0; i < 4; ++i) {
            #pragma unroll
            for (int reg = 0; reg < 4; ++reg) {
                const int r = m0 + (w << 6) + (i << 4) + (quad << 2) + reg;
                const int b = r >> 11, s = r & 2047;
                float v[4];
                #pragma unroll
                for (int nt = 0; nt < 4; ++nt) v[nt] = acc[i][nt][reg] + bcol[nt];
                float mx = fmaxf(fmaxf(v[0], v[1]), fmaxf(v[2], v[3]));
                #pragma unroll
                for (int msk = 1; msk < 16; msk <<= 1) mx = fmaxf(mx, __shfl_xor(mx, msk));
                float e[4], ssum = 0.f;
                #pragma unroll
                for (int nt = 0; nt < 4; ++nt) { e[nt] = __expf(v[nt] - mx); ssum += e[nt]; }
                #pragma unroll
                for (int msk = 1; msk < 16; msk <<= 1) ssum += __shfl_xor(ssum, msk);
                float inv = 1.0f / ssum;
                short* o = dst + ((size_t)((b << 3) + h) * 2048 + s) * 64 + l;
                #pragma unroll
                for (int nt = 0; nt < 4; ++nt)
                    o[nt << 4] = f2bf(sqrtf(e[nt] * inv));
            }
        }
    } else {
        // V: store transposed directly, vt[b,h,d,s]; lane owns 4 consecutive s
        float bcol[4];
        #pragma unroll
        for (int nt = 0; nt < 4; ++nt) bcol[nt] = bv[(h << 6) + (nt << 4) + l];
        #pragma unroll
        for (int i = 0; i < 4; ++i) {
            const int sb = m0 + (w << 6) + (i << 4) + (quad << 2);
            const int b = sb >> 11, s = sb & 2047;
            #pragma unroll
            for (int nt = 0; nt < 4; ++nt) {
                const int d = (nt << 4) + l;
                bf16x4 pk;
                #pragma unroll
                for (int reg = 0; reg < 4; ++reg)
                    pk[reg] = f2bf(acc[i][nt][reg] + bcol[nt]);
                *(bf16x4*)(vt + ((size_t)((b << 3) + h) * 64 + d) * 2048 + s) = pk;
            }
        }
    }
}

// ---------------------------------------------------------------------------
// Kernel 2: attention. Grid (32, 16), 256 threads = 4 waves. (unchanged)
// ---------------------------------------------------------------------------
__global__ __launch_bounds__(256, 4) void attn_mfma(
    const short* __restrict__ sp, const short* __restrict__ sq,
    const short* __restrict__ vt, short* __restrict__ attB)
{
    __shared__ short sqT[2][64 * 72];           // [j][d] staged sq tile
    __shared__ short vtT[2][64 * 72];           // [d][j] staged vt tile
    __shared__ short Pb[4][16 * 72];            // per-wave P [row][j]
    __shared__ float denB[4][16];
    const int bh = blockIdx.y;
    const int m0 = blockIdx.x << 6;
    const int tid = threadIdx.x;
    const int w = tid >> 6, lane = tid & 63;
    const int l = lane & 15, quad = lane >> 4;

    const short* spB = sp + (size_t)bh * 2048 * 64;
    const short* sqB = sq + (size_t)bh * 2048 * 64;
    const short* vtB = vt + (size_t)bh * 64 * 2048;

    // persistent sp frags (B-operand): lane l holds sp row (m0+w*16+l)
    const short* apr = spB + (size_t)(m0 + w * 16 + l) * 64 + quad * 8;
    short8 aq0 = *(const short8*)(apr);
    short8 aq1 = *(const short8*)(apr + 32);

    // staging assignment: thread -> tile row (tid>>2), 16-short col (tid&3)*16
    const int srow = tid >> 2;
    const int scol = (tid & 3) * 16;
    const short* sqG = sqB + (size_t)srow * 64 + scol;   // + j0*64 per jt
    const short* vtG = vtB + (size_t)srow * 2048 + scol; // + j0 per jt (cols j)
    const int ldsOff = srow * 72 + scol;

    // prologue: stage jt=0 into buffer 0
    {
        short8 a0 = *(const short8*)(sqG);
        short8 a1 = *(const short8*)(sqG + 8);
        short8 b0 = *(const short8*)(vtG);
        short8 b1 = *(const short8*)(vtG + 8);
        *(short8*)(&sqT[0][ldsOff])     = a0;
        *(short8*)(&sqT[0][ldsOff + 8]) = a1;
        *(short8*)(&vtT[0][ldsOff])     = b0;
        *(short8*)(&vtT[0][ldsOff + 8]) = b1;
    }
    __syncthreads();

    const f32x4 z4 = {0.f, 0.f, 0.f, 0.f};
    f32x4 acc[4] = {z4, z4, z4, z4};
    float den = 0.f;
    short* Pw = &Pb[w][0];

    #pragma unroll 1
    for (int jt = 0; jt < 32; ++jt) {
        const int cb = jt & 1, nb = cb ^ 1;
        const int j0n = ((jt + 1) & 31) << 6;   // wrap: harmless re-stage
        // global loads for jt+1 (latency covered by compute below)
        short8 na0 = *(const short8*)(sqG + (size_t)j0n * 64);
        short8 na1 = *(const short8*)(sqG + (size_t)j0n * 64 + 8);
        short8 nb0 = *(const short8*)(vtG + j0n);
        short8 nb1 = *(const short8*)(vtG + j0n + 8);

        // QK^T transposed: C[j][r] -> lane l = Q-row, quad*4+reg = j-local
        const short* sqL = &sqT[cb][0];
        #pragma unroll
        for (int nt = 0; nt < 4; ++nt) {
            const short* ar = sqL + (nt * 16 + l) * 72 + quad * 8;
            short8 sa0 = *(const short8*)(ar);
            short8 sa1 = *(const short8*)(ar + 32);
            f32x4 p = MFMA(sa0, aq0, z4);
            p = MFMA(sa1, aq1, p);
            float wv[4];
            #pragma unroll
            for (int reg = 0; reg < 4; ++reg) {
                // bc in [0,1]; acos(x)^2 = 2u + u^2/3 + ..., u = 1-x
                float u = fmaxf(1.0f - p[reg], 0.0f);
                float t = 0.000922f;
                t = fmaf(t, u, 0.00152228f);
                t = fmaf(t, u, 0.00384801f);
                t = fmaf(t, u, 0.01015873f);
                t = fmaf(t, u, 0.02857143f);
                t = fmaf(t, u, 0.08888889f);
                t = fmaf(t, u, 0.33333333f);
                t = fmaf(t, u, 2.0f);
                float e = __expf(-u * t);
                wv[reg] = e;
                den += e;
            }
            // pack 4 consecutive-j bf16 (trunc; bias cancels in num/den)
            uint2 pk;
            pk.x = (__float_as_uint(wv[0]) >> 16) | (__float_as_uint(wv[1]) & 0xffff0000u);
            pk.y = (__float_as_uint(wv[2]) >> 16) | (__float_as_uint(wv[3]) & 0xffff0000u);
            *(uint2*)(&Pw[l * 72 + nt * 16 + quad * 4]) = pk;
        }

        // PV: P rows as A-frags (2 reads feed 8 MFMAs), V B-frags from LDS
        const short* pr = Pw + l * 72 + quad * 8;
        short8 pa0 = *(const short8*)(pr);
        short8 pa1 = *(const short8*)(pr + 32);
        const short* vL = &vtT[cb][0];
        #pragma unroll
        for (int t4 = 0; t4 < 4; ++t4) {
            const short* vr = vL + (t4 * 16 + l) * 72 + quad * 8;
            short8 vb0 = *(const short8*)(vr);
            short8 vb1 = *(const short8*)(vr + 32);
            acc[t4] = MFMA(pa0, vb0, acc[t4]);
            acc[t4] = MFMA(pa1, vb1, acc[t4]);
        }

        // write next tiles into the other buffer, then single barrier
        *(short8*)(&sqT[nb][ldsOff])     = na0;
        *(short8*)(&sqT[nb][ldsOff + 8]) = na1;
        *(short8*)(&vtT[nb][ldsOff])     = nb0;
        *(short8*)(&vtT[nb][ldsOff + 8]) = nb1;
        __syncthreads();
    }

    // den: each quad covered different j -> sum across quads (lane row = l)
    den += __shfl_xor(den, 16);
    den += __shfl_xor(den, 32);
    if (lane < 16) denB[w][l] = den;
    // wave-synchronous LDS: compiler inserts lgkmcnt wait
    float invd[4];
    #pragma unroll
    for (int reg = 0; reg < 4; ++reg)
        invd[reg] = 1.0f / denB[w][quad * 4 + reg];

    const int b = bh >> 3, hh = bh & 7;
    #pragma unroll
    for (int t4 = 0; t4 < 4; ++t4)
        #pragma unroll
        for (int reg = 0; reg < 4; ++reg) {
            const int row = m0 + w * 16 + quad * 4 + reg;
            attB[((size_t)(b * 2048 + row)) * 512 + hh * 64 + t4 * 16 + l] =
                f2bf(acc[t4][reg] * invd[reg]);
        }
}

// ---------------------------------------------------------------------------
// Kernel 3: out = attB[4096][512](bf16) @ Wo + bo -> fp32. (unchanged R9)
// Grid (16, 32), 256 threads = 4 waves. Tile 128 rows x 64 cols, K=512.
// ---------------------------------------------------------------------------
__global__ __launch_bounds__(256, 3) void out_mfma(
    const short* __restrict__ attB, const short* __restrict__ wot,
    const float* __restrict__ bo, float* __restrict__ out)
{
    __shared__ short As[2][128 * 32];     // 8KB per buffer
    __shared__ short Bs[2][64 * 32];      // 4KB per buffer
    const int nb0 = blockIdx.x << 6;      // 64-col tile
    const int m0 = blockIdx.y << 7;
    const int tid = threadIdx.x;
    const int w = tid >> 6, lane = tid & 63;
    const int l = lane & 15, quad = lane >> 4;

    const short* gA = attB + (size_t)(m0  + (w << 4) + (lane >> 2)) * 512 + ((lane & 3) << 3);
    const short* gB = wot  + (size_t)(nb0 + (w << 4) + (lane >> 2)) * 512 + ((lane & 3) << 3);

    // prologue: k-tile 0 -> buffer 0 (A: chunks w, w+4; B: chunk w)
    gld_lds16(gA,            &As[0][w << 9]);
    gld_lds16(gA + 64 * 512, &As[0][(w + 4) << 9]);
    gld_lds16(gB,            &Bs[0][w << 9]);
    __syncthreads();

    const f32x4 z4 = {0.f, 0.f, 0.f, 0.f};
    f32x4 acc[4][2];
    #pragma unroll
    for (int i = 0; i < 4; ++i) { acc[i][0] = z4; acc[i][1] = z4; }

    const int rsel = (w >> 1) << 6;   // wave row offset (0/64)
    const int csel = (w & 1) << 5;    // wave col offset (0/32)

    for (int kt = 0; kt < 16; ++kt) {
        const int cb = kt & 1, nbuf = cb ^ 1;
        if (kt < 15) {
            const int k0 = (kt + 1) << 5;
            gld_lds16(gA + k0,            &As[nbuf][w << 9]);
            gld_lds16(gA + k0 + 64 * 512, &As[nbuf][(w + 4) << 9]);
            gld_lds16(gB + k0,            &Bs[nbuf][w << 9]);
        }
        const short* Al = &As[cb][rsel << 5];
        const short* Bl = &Bs[cb][csel << 5];
        short8 af[4], bfr[2];
        #pragma unroll
        for (int i = 0; i < 4; ++i)
            af[i] = *(const short8*)(Al + (((i << 4) + l) << 5) + (quad << 3));
        #pragma unroll
        for (int j = 0; j < 2; ++j)
            bfr[j] = *(const short8*)(Bl + (((j << 4) + l) << 5) + (quad << 3));
        #pragma unroll
        for (int i = 0; i < 4; ++i) {
            acc[i][0] = MFMA(af[i], bfr[0], acc[i][0]);
            acc[i][1] = MFMA(af[i], bfr[1], acc[i][1]);
        }
        __syncthreads();
    }

    const int n0 = nb0 + csel;
    float bcol[2];
    bcol[0] = bo[n0 + l];
    bcol[1] = bo[n0 + 16 + l];
    #pragma unroll
    for (int i = 0; i < 4; ++i)
        #pragma unroll
        for (int reg = 0; reg < 4; ++reg) {
            const int m = m0 + rsel + (i << 4) + (quad << 2) + reg;
            float* o = out + (size_t)m * 1024 + n0 + l;
            o[0]  = acc[i][0][reg] + bcol[0];
            o[16] = acc[i][1][reg] + bcol[1];
        }
}

// ---------------------------------------------------------------------------
extern "C" void kernel_launch(void* const* d_in, const int* in_sizes, int n_in,
                              void* d_out, int out_size, void* d_ws, size_t ws_size,
                              hipStream_t stream) {
    const float* xr = (const float*)d_in[0];
    const float* xi = (const float*)d_in[1];
    const float* Wq = (const float*)d_in[2];
    const float* bq = (const float*)d_in[3];
    const float* Wk = (const float*)d_in[4];
    const float* bk = (const float*)d_in[5];
    const float* Wv = (const float*)d_in[6];
    const float* bv = (const float*)d_in[7];
    const float* Wo = (const float*)d_in[8];
    const float* bo = (const float*)d_in[9];
    float* out = (float*)d_out;

    short* base = (short*)d_ws;
    short* xb   = base;                      // 4096*1024
    short* wqt  = xb  + 4194304;             // 512*1024  } contiguous =>
    short* wkt  = wqt + 524288;              // 512*1024  } wcat[1536][1024]
    short* wvt  = wkt + 524288;              // 512*1024  }
    short* wot  = wvt + 524288;              // 1024*512
    short* spW  = wot + 524288;              // 16*2048*64
    short* sqW  = spW + 2097152;
    short* vtW  = sqW + 2097152;             // [b,h,d,s]
    short* attB = vtW + 2097152;             // 4096*512
    // total = 14,680,064 shorts = 28 MB

    hipLaunchKernelGGL(convert_x, dim3(4096), dim3(256), 0, stream, xr, xi, xb);
    hipLaunchKernelGGL(transpose_w, dim3(32, 32, 4), dim3(256), 0, stream,
                       Wq, Wk, Wv, Wo, wqt, wkt, wvt, wot);
    hipLaunchKernelGGL(qkv_mfma, dim3(24, 32), dim3(128), 0, stream,
                       xb, wqt, bq, bk, bv, spW, sqW, vtW);
    hipLaunchKernelGGL(attn_mfma, dim3(32, 16), dim3(256), 0, stream,
                       spW, sqW, vtW, attB);
    hipLaunchKernelGGL(out_mfma, dim3(16, 32), dim3(256), 0, stream,
                       attB, wot, bo, out);
}

// Round 4
// 185.716 us; speedup vs baseline: 1.0180x; 1.0180x over previous
//
#include <hip/hip_runtime.h>
#include <math.h>

// GeoAttention on gfx950: B=2, S=2048, DIM=512, H=8, HD=64.
// bf16 MFMA (16x16x32) everywhere, fp32 accumulate.
// R12: attn_mfma was VALU-bound (VALUBusy 58%, MfmaUtil 12%): ~15 VALU ops
// per score element (poly8+exp+sub+max+den+pack) x 67M elements. Changes:
//  (1) acos^2 polynomial + den now packed fp32 over float2 (v_pk_fma_f32,
//      full-rate on gfx950) — halves the poly cost;
//  (2) Q-fragment negated once + MFMA C-init=1 gives u = 1-bc for free;
//  (3) LDS tiles restride 72->64 shorts + XOR-16B-slot swizzle (m214
//      pattern) on sqT/vtT/Pb: 2-way max per phase, LDS 46.6->40.3 KB.
// qkv_mfma (R11 tiling, <53us) / out_mfma unchanged.

typedef __attribute__((ext_vector_type(8))) short short8;
typedef __attribute__((ext_vector_type(4))) short bf16x4;
typedef __attribute__((ext_vector_type(4))) float f32x4;
typedef __attribute__((ext_vector_type(2))) float f32x2;

#define MFMA(a, b, c) __builtin_amdgcn_mfma_f32_16x16x32_bf16((a), (b), (c), 0, 0, 0)

static __device__ __forceinline__ short f2bf(float f) {
    unsigned u = __float_as_uint(f);
    u += 0x7fffu + ((u >> 16) & 1u);          // round-to-nearest-even
    return (short)(u >> 16);
}

// global -> LDS direct DMA, 16B per lane, wave-uniform LDS base + lane*16
static __device__ __forceinline__ void gld_lds16(const short* g, short* l) {
    __builtin_amdgcn_global_load_lds(
        (const __attribute__((address_space(1))) unsigned int*)g,
        (__attribute__((address_space(3))) unsigned int*)l, 16, 0, 0);
}

// ---------------------------------------------------------------------------
// Prep 1: xb[4096][1024] bf16 = concat(x_real, x_imag)
// ---------------------------------------------------------------------------
__global__ __launch_bounds__(256) void convert_x(
    const float* __restrict__ xr, const float* __restrict__ xi,
    short* __restrict__ xb)
{
    int idx = blockIdx.x * 256 + threadIdx.x;
    int e = idx << 2;
    int m = e >> 10, k = e & 1023;
    const float* src = (k < 512) ? xr : xi;
    float4 t = *(const float4*)(src + (size_t)m * 512 + (k & 511));
    unsigned lo = (unsigned short)f2bf(t.x) | ((unsigned)(unsigned short)f2bf(t.y) << 16);
    unsigned hi = (unsigned short)f2bf(t.z) | ((unsigned)(unsigned short)f2bf(t.w) << 16);
    uint2 o; o.x = lo; o.y = hi;
    *(uint2*)(xb + e) = o;
}

// ---------------------------------------------------------------------------
// Prep 2: transpose + convert weights to bf16, n-major [N][K].
// wqt/wkt/wvt are contiguous in the workspace => single wcat[1536][1024].
// ---------------------------------------------------------------------------
__global__ __launch_bounds__(256) void transpose_w(
    const float* __restrict__ Wq, const float* __restrict__ Wk,
    const float* __restrict__ Wv, const float* __restrict__ Wo,
    short* __restrict__ wqt, short* __restrict__ wkt,
    short* __restrict__ wvt, short* __restrict__ wot)
{
    __shared__ float t[32][33];
    const int z = blockIdx.z;
    const float* src = (z == 0) ? Wq : (z == 1) ? Wk : (z == 2) ? Wv : Wo;
    short* dst = (z == 0) ? wqt : (z == 1) ? wkt : (z == 2) ? wvt : wot;
    const int K = (z < 3) ? 1024 : 512;
    const int N = (z < 3) ? 512 : 1024;
    const int n0 = blockIdx.x << 5, k0 = blockIdx.y << 5;
    if (n0 >= N || k0 >= K) return;
    const int tx = threadIdx.x & 31, ty = threadIdx.x >> 5;
    #pragma unroll
    for (int i = 0; i < 4; ++i)
        t[ty + 8 * i][tx] = src[(size_t)(k0 + ty + 8 * i) * N + n0 + tx];
    __syncthreads();
    #pragma unroll
    for (int i = 0; i < 4; ++i)
        dst[(size_t)(n0 + ty + 8 * i) * K + k0 + tx] = f2bf(t[tx][ty + 8 * i]);
}

// ---------------------------------------------------------------------------
// Kernel 1: QKV projection. Grid (24, 32), 128 threads = 2 waves.
// Block tile = 128 rows x 64 cols over K=1024 (BK=32, 32 steps).
// jb: op = jb>>3 (0=Q,1=K,2=V), h = jb&7. Wave w owns rows [m0+w*64, +64)
// of head h => fused softmax(64)+sqrt epilogue per wave. (unchanged R11)
// ---------------------------------------------------------------------------
__global__ __launch_bounds__(128, 4) void qkv_mfma(
    const short* __restrict__ xb, const short* __restrict__ wcat,
    const float* __restrict__ bq, const float* __restrict__ bk,
    const float* __restrict__ bv,
    short* __restrict__ sp, short* __restrict__ sq, short* __restrict__ vt)
{
    __shared__ short As[2][128 * 32];     // [row][k] 8KB per buffer
    __shared__ short Bs[2][64 * 32];      // [col][k] 4KB per buffer
    const int jb = blockIdx.x;            // 0..23
    const int m0 = blockIdx.y << 7;       // 128-row tile
    const int tid = threadIdx.x;
    const int w = tid >> 6, lane = tid & 63;
    const int l = lane & 15, quad = lane >> 4;

    // staging: 1KB chunk = 16 rows x 64B; lane -> row (lane>>2), seg (lane&3)*8
    // wave w stages A-chunks {4w..4w+3}, B-chunks {2w, 2w+1}
    const int srow = lane >> 2;
    const int sseg = (lane & 3) << 3;
    const short* gA = xb   + (size_t)(m0        + (w << 6) + srow) * 1024 + sseg;
    const short* gB = wcat + (size_t)((jb << 6) + (w << 5) + srow) * 1024 + sseg;

    // prologue: k-tile 0 -> buffer 0
    #pragma unroll
    for (int t = 0; t < 4; ++t)
        gld_lds16(gA + t * 16 * 1024, &As[0][((w << 2) + t) << 9]);
    #pragma unroll
    for (int t = 0; t < 2; ++t)
        gld_lds16(gB + t * 16 * 1024, &Bs[0][((w << 1) + t) << 9]);
    __syncthreads();

    const f32x4 z4 = {0.f, 0.f, 0.f, 0.f};
    f32x4 acc[4][4];
    #pragma unroll
    for (int i = 0; i < 4; ++i)
        #pragma unroll
        for (int j = 0; j < 4; ++j) acc[i][j] = z4;

    for (int kt = 0; kt < 32; ++kt) {
        const int cb = kt & 1, nb = cb ^ 1;
        if (kt < 31) {
            const int k0 = (kt + 1) << 5;
            #pragma unroll
            for (int t = 0; t < 4; ++t)
                gld_lds16(gA + k0 + t * 16 * 1024, &As[nb][((w << 2) + t) << 9]);
            #pragma unroll
            for (int t = 0; t < 2; ++t)
                gld_lds16(gB + k0 + t * 16 * 1024, &Bs[nb][((w << 1) + t) << 9]);
        }
        const short* Al = &As[cb][(w << 6) << 5];   // wave rows: w*64
        const short* Bl = &Bs[cb][0];
        short8 af[4], bfr[4];
        #pragma unroll
        for (int i = 0; i < 4; ++i)
            af[i] = *(const short8*)(Al + (((i << 4) + l) << 5) + (quad << 3));
        #pragma unroll
        for (int j = 0; j < 4; ++j)
            bfr[j] = *(const short8*)(Bl + (((j << 4) + l) << 5) + (quad << 3));
        #pragma unroll
        for (int i = 0; i < 4; ++i)
            #pragma unroll
            for (int j = 0; j < 4; ++j)
                acc[i][j] = MFMA(af[i], bfr[j], acc[i][j]);
        __syncthreads();
    }

    const int op = jb >> 3;               // 0=Q 1=K 2=V
    const int h  = jb & 7;                // head for this block

    if (op < 2) {
        short* dst = (op == 0) ? sp : sq;
        const float* bias = (op == 0) ? bq : bk;
        float bcol[4];
        #pragma unroll
        for (int nt = 0; nt < 4; ++nt) bcol[nt] = bias[(h << 6) + (nt << 4) + l];
        #pragma unroll
        for (int i = 0; i < 4; ++i) {
            #pragma unroll
            for (int reg = 0; reg < 4; ++reg) {
                const int r = m0 + (w << 6) + (i << 4) + (quad << 2) + reg;
                const int b = r >> 11, s = r & 2047;
                float v[4];
                #pragma unroll
                for (int nt = 0; nt < 4; ++nt) v[nt] = acc[i][nt][reg] + bcol[nt];
                float mx = fmaxf(fmaxf(v[0], v[1]), fmaxf(v[2], v[3]));
                #pragma unroll
                for (int msk = 1; msk < 16; msk <<= 1) mx = fmaxf(mx, __shfl_xor(mx, msk));
                float e[4], ssum = 0.f;
                #pragma unroll
                for (int nt = 0; nt < 4; ++nt) { e[nt] = __expf(v[nt] - mx); ssum += e[nt]; }
                #pragma unroll
                for (int msk = 1; msk < 16; msk <<= 1) ssum += __shfl_xor(ssum, msk);
                float inv = 1.0f / ssum;
                short* o = dst + ((size_t)((b << 3) + h) * 2048 + s) * 64 + l;
                #pragma unroll
                for (int nt = 0; nt < 4; ++nt)
                    o[nt << 4] = f2bf(sqrtf(e[nt] * inv));
            }
        }
    } else {
        // V: store transposed directly, vt[b,h,d,s]; lane owns 4 consecutive s
        float bcol[4];
        #pragma unroll
        for (int nt = 0; nt < 4; ++nt) bcol[nt] = bv[(h << 6) + (nt << 4) + l];
        #pragma unroll
        for (int i = 0; i < 4; ++i) {
            const int sb = m0 + (w << 6) + (i << 4) + (quad << 2);
            const int b = sb >> 11, s = sb & 2047;
            #pragma unroll
            for (int nt = 0; nt < 4; ++nt) {
                const int d = (nt << 4) + l;
                bf16x4 pk;
                #pragma unroll
                for (int reg = 0; reg < 4; ++reg)
                    pk[reg] = f2bf(acc[i][nt][reg] + bcol[nt]);
                *(bf16x4*)(vt + ((size_t)((b << 3) + h) * 64 + d) * 2048 + s) = pk;
            }
        }
    }
}

// ---------------------------------------------------------------------------
// Kernel 2: attention. Grid (32, 16), 256 threads = 4 waves.
// R12 layout: LDS tiles stride 64 shorts (128B rows, 8x16B slots), slot
// s of row r stored at (s ^ (r&7)) — XOR swizzle, 2-way max per phase.
// QK: u = MFMA(sq, -sp, ones) = 1-bc directly; poly+den in packed f32x2.
// ---------------------------------------------------------------------------
__global__ __launch_bounds__(256, 4) void attn_mfma(
    const short* __restrict__ sp, const short* __restrict__ sq,
    const short* __restrict__ vt, short* __restrict__ attB)
{
    __shared__ __align__(16) short sqT[2][64 * 64];   // [j][d] swizzled
    __shared__ __align__(16) short vtT[2][64 * 64];   // [d][j] swizzled
    __shared__ __align__(16) short Pb[4][16 * 64];    // per-wave P, swizzled
    __shared__ float denB[4][16];
    const int bh = blockIdx.y;
    const int m0 = blockIdx.x << 6;
    const int tid = threadIdx.x;
    const int w = tid >> 6, lane = tid & 63;
    const int l = lane & 15, quad = lane >> 4;
    const int l7 = l & 7;

    const short* spB = sp + (size_t)bh * 2048 * 64;
    const short* sqB = sq + (size_t)bh * 2048 * 64;
    const short* vtB = vt + (size_t)bh * 64 * 2048;

    // persistent sp frags (B-operand): lane l holds sp row (m0+w*16+l).
    // negate once (bf16 sign flip) so MFMA(sq, -sp, 1) = 1 - bc = u.
    const short* apr = spB + (size_t)(m0 + w * 16 + l) * 64 + quad * 8;
    short8 aq0 = *(const short8*)(apr);
    short8 aq1 = *(const short8*)(apr + 32);
    short8 nq0 = aq0 ^ (short)0x8000;
    short8 nq1 = aq1 ^ (short)0x8000;

    // staging: thread -> tile row (tid>>2), 32B chunk (tid&3); swizzled dest
    const int srow = tid >> 2;
    const int scol = (tid & 3) * 16;
    const short* sqG = sqB + (size_t)srow * 64 + scol;   // + j0*64 per jt
    const short* vtG = vtB + (size_t)srow * 2048 + scol; // + j0 per jt
    const int sl0 = (tid & 3) << 1;                      // 16B slot base
    const int sw0 = srow * 64 + (((sl0    ) ^ (srow & 7)) << 3);
    const int sw1 = srow * 64 + (((sl0 | 1) ^ (srow & 7)) << 3);

    // reader slot offset: rows read are (16*k + l) so row&7 == l7 everywhere
    const int sRd = (quad ^ l7) << 3;     // slot quad; ^32 gives slot quad+4

    // prologue: stage jt=0 into buffer 0
    {
        short8 a0 = *(const short8*)(sqG);
        short8 a1 = *(const short8*)(sqG + 8);
        short8 b0 = *(const short8*)(vtG);
        short8 b1 = *(const short8*)(vtG + 8);
        *(short8*)(&sqT[0][sw0]) = a0;
        *(short8*)(&sqT[0][sw1]) = a1;
        *(short8*)(&vtT[0][sw0]) = b0;
        *(short8*)(&vtT[0][sw1]) = b1;
    }
    __syncthreads();

    const f32x4 z4 = {0.f, 0.f, 0.f, 0.f};
    const f32x4 ones4 = {1.f, 1.f, 1.f, 1.f};
    f32x4 acc[4] = {z4, z4, z4, z4};
    f32x2 den2 = {0.f, 0.f};
    short* Pw = &Pb[w][0];

    #pragma unroll 1
    for (int jt = 0; jt < 32; ++jt) {
        const int cb = jt & 1, nb = cb ^ 1;
        const int j0n = ((jt + 1) & 31) << 6;   // wrap: harmless re-stage
        // global loads for jt+1 (latency covered by compute below)
        short8 na0 = *(const short8*)(sqG + (size_t)j0n * 64);
        short8 na1 = *(const short8*)(sqG + (size_t)j0n * 64 + 8);
        short8 nb0 = *(const short8*)(vtG + j0n);
        short8 nb1 = *(const short8*)(vtG + j0n + 8);

        // QK^T transposed: lane l = Q-row, quad*4+reg = j-local; u = 1-bc
        const short* sqL = &sqT[cb][0];
        #pragma unroll
        for (int nt = 0; nt < 4; ++nt) {
            const short* ar = sqL + ((nt * 16 + l) << 6);
            short8 sa0 = *(const short8*)(ar + sRd);
            short8 sa1 = *(const short8*)(ar + (sRd ^ 32));
            f32x4 p = MFMA(sa0, nq0, ones4);
            p = MFMA(sa1, nq1, p);
            // acos(1-u)^2 = u * poly(u); packed f32x2 math (v_pk_fma_f32)
            f32x2 u01 = {p[0], p[1]};
            f32x2 u23 = {p[2], p[3]};
            const f32x2 zz = {0.f, 0.f};
#if __has_builtin(__builtin_elementwise_max)
            u01 = __builtin_elementwise_max(u01, zz);
            u23 = __builtin_elementwise_max(u23, zz);
#else
            u01.x = fmaxf(u01.x, 0.f); u01.y = fmaxf(u01.y, 0.f);
            u23.x = fmaxf(u23.x, 0.f); u23.y = fmaxf(u23.y, 0.f);
#endif
            f32x2 t01 = {0.000922f, 0.000922f};
            f32x2 t23 = t01;
            t01 = t01 * u01 + 0.00152228f;  t23 = t23 * u23 + 0.00152228f;
            t01 = t01 * u01 + 0.00384801f;  t23 = t23 * u23 + 0.00384801f;
            t01 = t01 * u01 + 0.01015873f;  t23 = t23 * u23 + 0.01015873f;
            t01 = t01 * u01 + 0.02857143f;  t23 = t23 * u23 + 0.02857143f;
            t01 = t01 * u01 + 0.08888889f;  t23 = t23 * u23 + 0.08888889f;
            t01 = t01 * u01 + 0.33333333f;  t23 = t23 * u23 + 0.33333333f;
            t01 = t01 * u01 + 2.0f;         t23 = t23 * u23 + 2.0f;
            f32x2 w01 = u01 * t01;
            f32x2 w23 = u23 * t23;
            float e0 = __expf(-w01.x), e1 = __expf(-w01.y);
            float e2 = __expf(-w23.x), e3 = __expf(-w23.y);
            f32x2 es = {e0 + e2, e1 + e3};
            den2 += es;
            // pack 4 consecutive-j bf16 (trunc; bias cancels in num/den)
            uint2 pk;
            pk.x = (__float_as_uint(e0) >> 16) | (__float_as_uint(e1) & 0xffff0000u);
            pk.y = (__float_as_uint(e2) >> 16) | (__float_as_uint(e3) & 0xffff0000u);
            // P row l, logical bytes 32*nt+8*quad -> swizzled slot
            *(uint2*)(&Pw[(l << 6) + ((((nt << 1) + (quad >> 1)) ^ l7) << 3)
                          + ((quad & 1) << 2)]) = pk;
        }

        // PV: P rows as A-frags, V B-frags from LDS (all swizzled reads)
        const short* pr = Pw + (l << 6);
        short8 pa0 = *(const short8*)(pr + sRd);
        short8 pa1 = *(const short8*)(pr + (sRd ^ 32));
        const short* vL = &vtT[cb][0];
        #pragma unroll
        for (int t4 = 0; t4 < 4; ++t4) {
            const short* vr = vL + ((t4 * 16 + l) << 6);
            short8 vb0 = *(const short8*)(vr + sRd);
            short8 vb1 = *(const short8*)(vr + (sRd ^ 32));
            acc[t4] = MFMA(pa0, vb0, acc[t4]);
            acc[t4] = MFMA(pa1, vb1, acc[t4]);
        }

        // write next tiles into the other buffer, then single barrier
        *(short8*)(&sqT[nb][sw0]) = na0;
        *(short8*)(&sqT[nb][sw1]) = na1;
        *(short8*)(&vtT[nb][sw0]) = nb0;
        *(short8*)(&vtT[nb][sw1]) = nb1;
        __syncthreads();
    }

    // den: each quad covered different j -> sum across quads (lane row = l)
    float den = den2.x + den2.y;
    den += __shfl_xor(den, 16);
    den += __shfl_xor(den, 32);
    if (lane < 16) denB[w][l] = den;
    // wave-synchronous LDS: compiler inserts lgkmcnt wait
    float invd[4];
    #pragma unroll
    for (int reg = 0; reg < 4; ++reg)
        invd[reg] = 1.0f / denB[w][quad * 4 + reg];

    const int b = bh >> 3, hh = bh & 7;
    #pragma unroll
    for (int t4 = 0; t4 < 4; ++t4)
        #pragma unroll
        for (int reg = 0; reg < 4; ++reg) {
            const int row = m0 + w * 16 + quad * 4 + reg;
            attB[((size_t)(b * 2048 + row)) * 512 + hh * 64 + t4 * 16 + l] =
                f2bf(acc[t4][reg] * invd[reg]);
        }
}

// ---------------------------------------------------------------------------
// Kernel 3: out = attB[4096][512](bf16) @ Wo + bo -> fp32. (unchanged)
// Grid (16, 32), 256 threads = 4 waves. Tile 128 rows x 64 cols, K=512.
// ---------------------------------------------------------------------------
__global__ __launch_bounds__(256, 3) void out_mfma(
    const short* __restrict__ attB, const short* __restrict__ wot,
    const float* __restrict__ bo, float* __restrict__ out)
{
    __shared__ short As[2][128 * 32];     // 8KB per buffer
    __shared__ short Bs[2][64 * 32];      // 4KB per buffer
    const int nb0 = blockIdx.x << 6;      // 64-col tile
    const int m0 = blockIdx.y << 7;
    const int tid = threadIdx.x;
    const int w = tid >> 6, lane = tid & 63;
    const int l = lane & 15, quad = lane >> 4;

    const short* gA = attB + (size_t)(m0  + (w << 4) + (lane >> 2)) * 512 + ((lane & 3) << 3);
    const short* gB = wot  + (size_t)(nb0 + (w << 4) + (lane >> 2)) * 512 + ((lane & 3) << 3);

    // prologue: k-tile 0 -> buffer 0 (A: chunks w, w+4; B: chunk w)
    gld_lds16(gA,            &As[0][w << 9]);
    gld_lds16(gA + 64 * 512, &As[0][(w + 4) << 9]);
    gld_lds16(gB,            &Bs[0][w << 9]);
    __syncthreads();

    const f32x4 z4 = {0.f, 0.f, 0.f, 0.f};
    f32x4 acc[4][2];
    #pragma unroll
    for (int i = 0; i < 4; ++i) { acc[i][0] = z4; acc[i][1] = z4; }

    const int rsel = (w >> 1) << 6;   // wave row offset (0/64)
    const int csel = (w & 1) << 5;    // wave col offset (0/32)

    for (int kt = 0; kt < 16; ++kt) {
        const int cb = kt & 1, nbuf = cb ^ 1;
        if (kt < 15) {
            const int k0 = (kt + 1) << 5;
            gld_lds16(gA + k0,            &As[nbuf][w << 9]);
            gld_lds16(gA + k0 + 64 * 512, &As[nbuf][(w + 4) << 9]);
            gld_lds16(gB + k0,            &Bs[nbuf][w << 9]);
        }
        const short* Al = &As[cb][rsel << 5];
        const short* Bl = &Bs[cb][csel << 5];
        short8 af[4], bfr[2];
        #pragma unroll
        for (int i = 0; i < 4; ++i)
            af[i] = *(const short8*)(Al + (((i << 4) + l) << 5) + (quad << 3));
        #pragma unroll
        for (int j = 0; j < 2; ++j)
            bfr[j] = *(const short8*)(Bl + (((j << 4) + l) << 5) + (quad << 3));
        #pragma unroll
        for (int i = 0; i < 4; ++i) {
            acc[i][0] = MFMA(af[i], bfr[0], acc[i][0]);
            acc[i][1] = MFMA(af[i], bfr[1], acc[i][1]);
        }
        __syncthreads();
    }

    const int n0 = nb0 + csel;
    float bcol[2];
    bcol[0] = bo[n0 + l];
    bcol[1] = bo[n0 + 16 + l];
    #pragma unroll
    for (int i = 0; i < 4; ++i)
        #pragma unroll
        for (int reg = 0; reg < 4; ++reg) {
            const int m = m0 + rsel + (i << 4) + (quad << 2) + reg;
            float* o = out + (size_t)m * 1024 + n0 + l;
            o[0]  = acc[i][0][reg] + bcol[0];
            o[16] = acc[i][1][reg] + bcol[1];
        }
}

// ---------------------------------------------------------------------------
extern "C" void kernel_launch(void* const* d_in, const int* in_sizes, int n_in,
                              void* d_out, int out_size, void* d_ws, size_t ws_size,
                              hipStream_t stream) {
    const float* xr = (const float*)d_in[0];
    const float* xi = (const float*)d_in[1];
    const float* Wq = (const float*)d_in[2];
    const float* bq = (const float*)d_in[3];
    const float* Wk = (const float*)d_in[4];
    const float* bk = (const float*)d_in[5];
    const float* Wv = (const float*)d_in[6];
    const float* bv = (const float*)d_in[7];
    const float* Wo = (const float*)d_in[8];
    const float* bo = (const float*)d_in[9];
    float* out = (float*)d_out;

    short* base = (short*)d_ws;
    short* xb   = base;                      // 4096*1024
    short* wqt  = xb  + 4194304;             // 512*1024  } contiguous =>
    short* wkt  = wqt + 524288;              // 512*1024  } wcat[1536][1024]
    short* wvt  = wkt + 524288;              // 512*1024  }
    short* wot  = wvt + 524288;              // 1024*512
    short* spW  = wot + 524288;              // 16*2048*64
    short* sqW  = spW + 2097152;
    short* vtW  = sqW + 2097152;             // [b,h,d,s]
    short* attB = vtW + 2097152;             // 4096*512
    // total = 14,680,064 shorts = 28 MB

    hipLaunchKernelGGL(convert_x, dim3(4096), dim3(256), 0, stream, xr, xi, xb);
    hipLaunchKernelGGL(transpose_w, dim3(32, 32, 4), dim3(256), 0, stream,
                       Wq, Wk, Wv, Wo, wqt, wkt, wvt, wot);
    hipLaunchKernelGGL(qkv_mfma, dim3(24, 32), dim3(128), 0, stream,
                       xb, wqt, bq, bk, bv, spW, sqW, vtW);
    hipLaunchKernelGGL(attn_mfma, dim3(32, 16), dim3(256), 0, stream,
                       spW, sqW, vtW, attB);
    hipLaunchKernelGGL(out_mfma, dim3(16, 32), dim3(256), 0, stream,
                       attB, wot, bo, out);
}

// Round 5
// 185.496 us; speedup vs baseline: 1.0192x; 1.0012x over previous
//
#include <hip/hip_runtime.h>
#include <math.h>

// GeoAttention on gfx950: B=2, S=2048, DIM=512, H=8, HD=64.
// bf16 MFMA (16x16x32) everywhere, fp32 accumulate.
// R13: qkv_mfma + out_mfma converted from double-buffer/vmcnt(0) to
// TRIPLE-buffer with prefetch distance 2 and COUNTED vmcnt (T3/T4, m218:
// counted-vs-drain0 +38-73%). Iter kt stages buf[kt+2]; before the raw
// s_barrier we wait s_waitcnt vmcnt(6) (qkv; 3 for out) so only the
// previous stage must land — the newest 6 loads stay in flight ACROSS the
// barrier. Removes the per-K-step latency exposure that kept MfmaUtil at 7%.
// attn_mfma (R12: packed-f32 poly, u=MFMA(sq,-sp,1), XOR-swizzled LDS)
// and prep kernels unchanged.

typedef __attribute__((ext_vector_type(8))) short short8;
typedef __attribute__((ext_vector_type(4))) short bf16x4;
typedef __attribute__((ext_vector_type(4))) float f32x4;
typedef __attribute__((ext_vector_type(2))) float f32x2;

#define MFMA(a, b, c) __builtin_amdgcn_mfma_f32_16x16x32_bf16((a), (b), (c), 0, 0, 0)

static __device__ __forceinline__ short f2bf(float f) {
    unsigned u = __float_as_uint(f);
    u += 0x7fffu + ((u >> 16) & 1u);          // round-to-nearest-even
    return (short)(u >> 16);
}

// global -> LDS direct DMA, 16B per lane, wave-uniform LDS base + lane*16
static __device__ __forceinline__ void gld_lds16(const short* g, short* l) {
    __builtin_amdgcn_global_load_lds(
        (const __attribute__((address_space(1))) unsigned int*)g,
        (__attribute__((address_space(3))) unsigned int*)l, 16, 0, 0);
}

// ---------------------------------------------------------------------------
// Prep 1: xb[4096][1024] bf16 = concat(x_real, x_imag)
// ---------------------------------------------------------------------------
__global__ __launch_bounds__(256) void convert_x(
    const float* __restrict__ xr, const float* __restrict__ xi,
    short* __restrict__ xb)
{
    int idx = blockIdx.x * 256 + threadIdx.x;
    int e = idx << 2;
    int m = e >> 10, k = e & 1023;
    const float* src = (k < 512) ? xr : xi;
    float4 t = *(const float4*)(src + (size_t)m * 512 + (k & 511));
    unsigned lo = (unsigned short)f2bf(t.x) | ((unsigned)(unsigned short)f2bf(t.y) << 16);
    unsigned hi = (unsigned short)f2bf(t.z) | ((unsigned)(unsigned short)f2bf(t.w) << 16);
    uint2 o; o.x = lo; o.y = hi;
    *(uint2*)(xb + e) = o;
}

// ---------------------------------------------------------------------------
// Prep 2: transpose + convert weights to bf16, n-major [N][K].
// wqt/wkt/wvt are contiguous in the workspace => single wcat[1536][1024].
// ---------------------------------------------------------------------------
__global__ __launch_bounds__(256) void transpose_w(
    const float* __restrict__ Wq, const float* __restrict__ Wk,
    const float* __restrict__ Wv, const float* __restrict__ Wo,
    short* __restrict__ wqt, short* __restrict__ wkt,
    short* __restrict__ wvt, short* __restrict__ wot)
{
    __shared__ float t[32][33];
    const int z = blockIdx.z;
    const float* src = (z == 0) ? Wq : (z == 1) ? Wk : (z == 2) ? Wv : Wo;
    short* dst = (z == 0) ? wqt : (z == 1) ? wkt : (z == 2) ? wvt : wot;
    const int K = (z < 3) ? 1024 : 512;
    const int N = (z < 3) ? 512 : 1024;
    const int n0 = blockIdx.x << 5, k0 = blockIdx.y << 5;
    if (n0 >= N || k0 >= K) return;
    const int tx = threadIdx.x & 31, ty = threadIdx.x >> 5;
    #pragma unroll
    for (int i = 0; i < 4; ++i)
        t[ty + 8 * i][tx] = src[(size_t)(k0 + ty + 8 * i) * N + n0 + tx];
    __syncthreads();
    #pragma unroll
    for (int i = 0; i < 4; ++i)
        dst[(size_t)(n0 + ty + 8 * i) * K + k0 + tx] = f2bf(t[tx][ty + 8 * i]);
}

// ---------------------------------------------------------------------------
// Kernel 1: QKV projection. Grid (24, 32), 128 threads = 2 waves.
// Block tile = 128 rows x 64 cols over K=1024 (BK=32, 32 steps).
// R13: triple-buffered LDS, stage distance 2, counted vmcnt(6) per step
// (6 gld_lds16/wave/stage; vmcnt(6) drains exactly the previous stage).
// jb: op = jb>>3 (0=Q,1=K,2=V), h = jb&7; wave w owns rows [m0+64w, +64).
// ---------------------------------------------------------------------------
__global__ __launch_bounds__(128, 4) void qkv_mfma(
    const short* __restrict__ xb, const short* __restrict__ wcat,
    const float* __restrict__ bq, const float* __restrict__ bk,
    const float* __restrict__ bv,
    short* __restrict__ sp, short* __restrict__ sq, short* __restrict__ vt)
{
    __shared__ short As[3][128 * 32];     // [row][k] 8KB per buffer
    __shared__ short Bs[3][64 * 32];      // [col][k] 4KB per buffer
    const int jb = blockIdx.x;            // 0..23
    const int m0 = blockIdx.y << 7;       // 128-row tile
    const int tid = threadIdx.x;
    const int w = tid >> 6, lane = tid & 63;
    const int l = lane & 15, quad = lane >> 4;

    // staging: 1KB chunk = 16 rows x 64B; lane -> row (lane>>2), seg (lane&3)*8
    // wave w stages A-chunks {4w..4w+3}, B-chunks {2w, 2w+1}
    const int srow = lane >> 2;
    const int sseg = (lane & 3) << 3;
    const short* gA = xb   + (size_t)(m0        + (w << 6) + srow) * 1024 + sseg;
    const short* gB = wcat + (size_t)((jb << 6) + (w << 5) + srow) * 1024 + sseg;

    auto STAGE = [&](int bb, int kk) {
        const int k0 = kk << 5;
        #pragma unroll
        for (int t = 0; t < 4; ++t)
            gld_lds16(gA + k0 + t * 16 * 1024, &As[bb][((w << 2) + t) << 9]);
        #pragma unroll
        for (int t = 0; t < 2; ++t)
            gld_lds16(gB + k0 + t * 16 * 1024, &Bs[bb][((w << 1) + t) << 9]);
    };

    // prologue: stage k-tiles 0,1 into buffers 0,1; wait buf0 only (vmcnt
    // leaves the newest 6 = buf1's loads in flight across the barrier)
    STAGE(0, 0);
    STAGE(1, 1);
    asm volatile("s_waitcnt vmcnt(6)" ::: "memory");
    __builtin_amdgcn_s_barrier();

    const f32x4 z4 = {0.f, 0.f, 0.f, 0.f};
    f32x4 acc[4][4];
    #pragma unroll
    for (int i = 0; i < 4; ++i)
        #pragma unroll
        for (int j = 0; j < 4; ++j) acc[i][j] = z4;

    int cb = 0, sb = 2;
    #pragma unroll 1
    for (int kt = 0; kt < 32; ++kt) {
        STAGE(sb, (kt + 2) & 31);         // wrap re-stage at kt=30,31: harmless
        const short* Al = &As[cb][(w << 6) << 5];   // wave rows: w*64
        const short* Bl = &Bs[cb][0];
        short8 af[4], bfr[4];
        #pragma unroll
        for (int i = 0; i < 4; ++i)
            af[i] = *(const short8*)(Al + (((i << 4) + l) << 5) + (quad << 3));
        #pragma unroll
        for (int j = 0; j < 4; ++j)
            bfr[j] = *(const short8*)(Bl + (((j << 4) + l) << 5) + (quad << 3));
        #pragma unroll
        for (int i = 0; i < 4; ++i)
            #pragma unroll
            for (int j = 0; j < 4; ++j)
                acc[i][j] = MFMA(af[i], bfr[j], acc[i][j]);
        // counted wait: drains the stage issued LAST iteration (the buffer
        // needed next step); this iteration's 6 loads stay in flight.
        asm volatile("s_waitcnt vmcnt(6)" ::: "memory");
        __builtin_amdgcn_s_barrier();
        cb = (cb == 2) ? 0 : cb + 1;
        sb = (sb == 2) ? 0 : sb + 1;
    }
    asm volatile("s_waitcnt vmcnt(0)" ::: "memory");

    const int op = jb >> 3;               // 0=Q 1=K 2=V
    const int h  = jb & 7;                // head for this block

    if (op < 2) {
        short* dst = (op == 0) ? sp : sq;
        const float* bias = (op == 0) ? bq : bk;
        float bcol[4];
        #pragma unroll
        for (int nt = 0; nt < 4; ++nt) bcol[nt] = bias[(h << 6) + (nt << 4) + l];
        #pragma unroll
        for (int i = 0; i < 4; ++i) {
            #pragma unroll
            for (int reg = 0; reg < 4; ++reg) {
                const int r = m0 + (w << 6) + (i << 4) + (quad << 2) + reg;
                const int b = r >> 11, s = r & 2047;
                float v[4];
                #pragma unroll
                for (int nt = 0; nt < 4; ++nt) v[nt] = acc[i][nt][reg] + bcol[nt];
                float mx = fmaxf(fmaxf(v[0], v[1]), fmaxf(v[2], v[3]));
                #pragma unroll
                for (int msk = 1; msk < 16; msk <<= 1) mx = fmaxf(mx, __shfl_xor(mx, msk));
                float e[4], ssum = 0.f;
                #pragma unroll
                for (int nt = 0; nt < 4; ++nt) { e[nt] = __expf(v[nt] - mx); ssum += e[nt]; }
                #pragma unroll
                for (int msk = 1; msk < 16; msk <<= 1) ssum += __shfl_xor(ssum, msk);
                float inv = 1.0f / ssum;
                short* o = dst + ((size_t)((b << 3) + h) * 2048 + s) * 64 + l;
                #pragma unroll
                for (int nt = 0; nt < 4; ++nt)
                    o[nt << 4] = f2bf(sqrtf(e[nt] * inv));
            }
        }
    } else {
        // V: store transposed directly, vt[b,h,d,s]; lane owns 4 consecutive s
        float bcol[4];
        #pragma unroll
        for (int nt = 0; nt < 4; ++nt) bcol[nt] = bv[(h << 6) + (nt << 4) + l];
        #pragma unroll
        for (int i = 0; i < 4; ++i) {
            const int sb2 = m0 + (w << 6) + (i << 4) + (quad << 2);
            const int b = sb2 >> 11, s = sb2 & 2047;
            #pragma unroll
            for (int nt = 0; nt < 4; ++nt) {
                const int d = (nt << 4) + l;
                bf16x4 pk;
                #pragma unroll
                for (int reg = 0; reg < 4; ++reg)
                    pk[reg] = f2bf(acc[i][nt][reg] + bcol[nt]);
                *(bf16x4*)(vt + ((size_t)((b << 3) + h) * 64 + d) * 2048 + s) = pk;
            }
        }
    }
}

// ---------------------------------------------------------------------------
// Kernel 2: attention. Grid (32, 16), 256 threads = 4 waves. (unchanged R12)
// LDS tiles stride 64 shorts (128B rows, 8x16B slots), slot s of row r at
// (s ^ (r&7)). QK: u = MFMA(sq, -sp, ones) = 1-bc; poly+den packed f32x2.
// ---------------------------------------------------------------------------
__global__ __launch_bounds__(256, 4) void attn_mfma(
    const short* __restrict__ sp, const short* __restrict__ sq,
    const short* __restrict__ vt, short* __restrict__ attB)
{
    __shared__ __align__(16) short sqT[2][64 * 64];   // [j][d] swizzled
    __shared__ __align__(16) short vtT[2][64 * 64];   // [d][j] swizzled
    __shared__ __align__(16) short Pb[4][16 * 64];    // per-wave P, swizzled
    __shared__ float denB[4][16];
    const int bh = blockIdx.y;
    const int m0 = blockIdx.x << 6;
    const int tid = threadIdx.x;
    const int w = tid >> 6, lane = tid & 63;
    const int l = lane & 15, quad = lane >> 4;
    const int l7 = l & 7;

    const short* spB = sp + (size_t)bh * 2048 * 64;
    const short* sqB = sq + (size_t)bh * 2048 * 64;
    const short* vtB = vt + (size_t)bh * 64 * 2048;

    // persistent sp frags (B-operand): lane l holds sp row (m0+w*16+l).
    // negate once (bf16 sign flip) so MFMA(sq, -sp, 1) = 1 - bc = u.
    const short* apr = spB + (size_t)(m0 + w * 16 + l) * 64 + quad * 8;
    short8 aq0 = *(const short8*)(apr);
    short8 aq1 = *(const short8*)(apr + 32);
    short8 nq0 = aq0 ^ (short)0x8000;
    short8 nq1 = aq1 ^ (short)0x8000;

    // staging: thread -> tile row (tid>>2), 32B chunk (tid&3); swizzled dest
    const int srow = tid >> 2;
    const int scol = (tid & 3) * 16;
    const short* sqG = sqB + (size_t)srow * 64 + scol;   // + j0*64 per jt
    const short* vtG = vtB + (size_t)srow * 2048 + scol; // + j0 per jt
    const int sl0 = (tid & 3) << 1;                      // 16B slot base
    const int sw0 = srow * 64 + (((sl0    ) ^ (srow & 7)) << 3);
    const int sw1 = srow * 64 + (((sl0 | 1) ^ (srow & 7)) << 3);

    // reader slot offset: rows read are (16*k + l) so row&7 == l7 everywhere
    const int sRd = (quad ^ l7) << 3;     // slot quad; ^32 gives slot quad+4

    // prologue: stage jt=0 into buffer 0
    {
        short8 a0 = *(const short8*)(sqG);
        short8 a1 = *(const short8*)(sqG + 8);
        short8 b0 = *(const short8*)(vtG);
        short8 b1 = *(const short8*)(vtG + 8);
        *(short8*)(&sqT[0][sw0]) = a0;
        *(short8*)(&sqT[0][sw1]) = a1;
        *(short8*)(&vtT[0][sw0]) = b0;
        *(short8*)(&vtT[0][sw1]) = b1;
    }
    __syncthreads();

    const f32x4 z4 = {0.f, 0.f, 0.f, 0.f};
    const f32x4 ones4 = {1.f, 1.f, 1.f, 1.f};
    f32x4 acc[4] = {z4, z4, z4, z4};
    f32x2 den2 = {0.f, 0.f};
    short* Pw = &Pb[w][0];

    #pragma unroll 1
    for (int jt = 0; jt < 32; ++jt) {
        const int cb = jt & 1, nb = cb ^ 1;
        const int j0n = ((jt + 1) & 31) << 6;   // wrap: harmless re-stage
        // global loads for jt+1 (latency covered by compute below)
        short8 na0 = *(const short8*)(sqG + (size_t)j0n * 64);
        short8 na1 = *(const short8*)(sqG + (size_t)j0n * 64 + 8);
        short8 nb0 = *(const short8*)(vtG + j0n);
        short8 nb1 = *(const short8*)(vtG + j0n + 8);

        // QK^T transposed: lane l = Q-row, quad*4+reg = j-local; u = 1-bc
        const short* sqL = &sqT[cb][0];
        #pragma unroll
        for (int nt = 0; nt < 4; ++nt) {
            const short* ar = sqL + ((nt * 16 + l) << 6);
            short8 sa0 = *(const short8*)(ar + sRd);
            short8 sa1 = *(const short8*)(ar + (sRd ^ 32));
            f32x4 p = MFMA(sa0, nq0, ones4);
            p = MFMA(sa1, nq1, p);
            // acos(1-u)^2 = u * poly(u); packed f32x2 math (v_pk_fma_f32)
            f32x2 u01 = {p[0], p[1]};
            f32x2 u23 = {p[2], p[3]};
            const f32x2 zz = {0.f, 0.f};
#if __has_builtin(__builtin_elementwise_max)
            u01 = __builtin_elementwise_max(u01, zz);
            u23 = __builtin_elementwise_max(u23, zz);
#else
            u01.x = fmaxf(u01.x, 0.f); u01.y = fmaxf(u01.y, 0.f);
            u23.x = fmaxf(u23.x, 0.f); u23.y = fmaxf(u23.y, 0.f);
#endif
            f32x2 t01 = {0.000922f, 0.000922f};
            f32x2 t23 = t01;
            t01 = t01 * u01 + 0.00152228f;  t23 = t23 * u23 + 0.00152228f;
            t01 = t01 * u01 + 0.00384801f;  t23 = t23 * u23 + 0.00384801f;
            t01 = t01 * u01 + 0.01015873f;  t23 = t23 * u23 + 0.01015873f;
            t01 = t01 * u01 + 0.02857143f;  t23 = t23 * u23 + 0.02857143f;
            t01 = t01 * u01 + 0.08888889f;  t23 = t23 * u23 + 0.08888889f;
            t01 = t01 * u01 + 0.33333333f;  t23 = t23 * u23 + 0.33333333f;
            t01 = t01 * u01 + 2.0f;         t23 = t23 * u23 + 2.0f;
            f32x2 w01 = u01 * t01;
            f32x2 w23 = u23 * t23;
            float e0 = __expf(-w01.x), e1 = __expf(-w01.y);
            float e2 = __expf(-w23.x), e3 = __expf(-w23.y);
            f32x2 es = {e0 + e2, e1 + e3};
            den2 += es;
            // pack 4 consecutive-j bf16 (trunc; bias cancels in num/den)
            uint2 pk;
            pk.x = (__float_as_uint(e0) >> 16) | (__float_as_uint(e1) & 0xffff0000u);
            pk.y = (__float_as_uint(e2) >> 16) | (__float_as_uint(e3) & 0xffff0000u);
            // P row l, logical bytes 32*nt+8*quad -> swizzled slot
            *(uint2*)(&Pw[(l << 6) + ((((nt << 1) + (quad >> 1)) ^ l7) << 3)
                          + ((quad & 1) << 2)]) = pk;
        }

        // PV: P rows as A-frags, V B-frags from LDS (all swizzled reads)
        const short* pr = Pw + (l << 6);
        short8 pa0 = *(const short8*)(pr + sRd);
        short8 pa1 = *(const short8*)(pr + (sRd ^ 32));
        const short* vL = &vtT[cb][0];
        #pragma unroll
        for (int t4 = 0; t4 < 4; ++t4) {
            const short* vr = vL + ((t4 * 16 + l) << 6);
            short8 vb0 = *(const short8*)(vr + sRd);
            short8 vb1 = *(const short8*)(vr + (sRd ^ 32));
            acc[t4] = MFMA(pa0, vb0, acc[t4]);
            acc[t4] = MFMA(pa1, vb1, acc[t4]);
        }

        // write next tiles into the other buffer, then single barrier
        *(short8*)(&sqT[nb][sw0]) = na0;
        *(short8*)(&sqT[nb][sw1]) = na1;
        *(short8*)(&vtT[nb][sw0]) = nb0;
        *(short8*)(&vtT[nb][sw1]) = nb1;
        __syncthreads();
    }

    // den: each quad covered different j -> sum across quads (lane row = l)
    float den = den2.x + den2.y;
    den += __shfl_xor(den, 16);
    den += __shfl_xor(den, 32);
    if (lane < 16) denB[w][l] = den;
    // wave-synchronous LDS: compiler inserts lgkmcnt wait
    float invd[4];
    #pragma unroll
    for (int reg = 0; reg < 4; ++reg)
        invd[reg] = 1.0f / denB[w][quad * 4 + reg];

    const int b = bh >> 3, hh = bh & 7;
    #pragma unroll
    for (int t4 = 0; t4 < 4; ++t4)
        #pragma unroll
        for (int reg = 0; reg < 4; ++reg) {
            const int row = m0 + w * 16 + quad * 4 + reg;
            attB[((size_t)(b * 2048 + row)) * 512 + hh * 64 + t4 * 16 + l] =
                f2bf(acc[t4][reg] * invd[reg]);
        }
}

// ---------------------------------------------------------------------------
// Kernel 3: out = attB[4096][512](bf16) @ Wo + bo -> fp32.
// R13: triple-buffer + counted vmcnt(3) (3 gld_lds16/wave/stage).
// Grid (16, 32), 256 threads = 4 waves. Tile 128 rows x 64 cols, K=512.
// ---------------------------------------------------------------------------
__global__ __launch_bounds__(256, 3) void out_mfma(
    const short* __restrict__ attB, const short* __restrict__ wot,
    const float* __restrict__ bo, float* __restrict__ out)
{
    __shared__ short As[3][128 * 32];     // 8KB per buffer
    __shared__ short Bs[3][64 * 32];      // 4KB per buffer
    const int nb0 = blockIdx.x << 6;      // 64-col tile
    const int m0 = blockIdx.y << 7;
    const int tid = threadIdx.x;
    const int w = tid >> 6, lane = tid & 63;
    const int l = lane & 15, quad = lane >> 4;

    const short* gA = attB + (size_t)(m0  + (w << 4) + (lane >> 2)) * 512 + ((lane & 3) << 3);
    const short* gB = wot  + (size_t)(nb0 + (w << 4) + (lane >> 2)) * 512 + ((lane & 3) << 3);

    auto STAGE = [&](int bb, int kk) {
        const int k0 = kk << 5;
        gld_lds16(gA + k0,            &As[bb][w << 9]);
        gld_lds16(gA + k0 + 64 * 512, &As[bb][(w + 4) << 9]);
        gld_lds16(gB + k0,            &Bs[bb][w << 9]);
    };

    STAGE(0, 0);
    STAGE(1, 1);
    asm volatile("s_waitcnt vmcnt(3)" ::: "memory");
    __builtin_amdgcn_s_barrier();

    const f32x4 z4 = {0.f, 0.f, 0.f, 0.f};
    f32x4 acc[4][2];
    #pragma unroll
    for (int i = 0; i < 4; ++i) { acc[i][0] = z4; acc[i][1] = z4; }

    const int rsel = (w >> 1) << 6;   // wave row offset (0/64)
    const int csel = (w & 1) << 5;    // wave col offset (0/32)

    int cb = 0, sb = 2;
    #pragma unroll 1
    for (int kt = 0; kt < 16; ++kt) {
        STAGE(sb, (kt + 2) & 15);         // wrap re-stage at kt=14,15: harmless
        const short* Al = &As[cb][rsel << 5];
        const short* Bl = &Bs[cb][csel << 5];
        short8 af[4], bfr[2];
        #pragma unroll
        for (int i = 0; i < 4; ++i)
            af[i] = *(const short8*)(Al + (((i << 4) + l) << 5) + (quad << 3));
        #pragma unroll
        for (int j = 0; j < 2; ++j)
            bfr[j] = *(const short8*)(Bl + (((j << 4) + l) << 5) + (quad << 3));
        #pragma unroll
        for (int i = 0; i < 4; ++i) {
            acc[i][0] = MFMA(af[i], bfr[0], acc[i][0]);
            acc[i][1] = MFMA(af[i], bfr[1], acc[i][1]);
        }
        asm volatile("s_waitcnt vmcnt(3)" ::: "memory");
        __builtin_amdgcn_s_barrier();
        cb = (cb == 2) ? 0 : cb + 1;
        sb = (sb == 2) ? 0 : sb + 1;
    }
    asm volatile("s_waitcnt vmcnt(0)" ::: "memory");

    const int n0 = nb0 + csel;
    float bcol[2];
    bcol[0] = bo[n0 + l];
    bcol[1] = bo[n0 + 16 + l];
    #pragma unroll
    for (int i = 0; i < 4; ++i)
        #pragma unroll
        for (int reg = 0; reg < 4; ++reg) {
            const int m = m0 + rsel + (i << 4) + (quad << 2) + reg;
            float* o = out + (size_t)m * 1024 + n0 + l;
            o[0]  = acc[i][0][reg] + bcol[0];
            o[16] = acc[i][1][reg] + bcol[1];
        }
}

// ---------------------------------------------------------------------------
extern "C" void kernel_launch(void* const* d_in, const int* in_sizes, int n_in,
                              void* d_out, int out_size, void* d_ws, size_t ws_size,
                              hipStream_t stream) {
    const float* xr = (const float*)d_in[0];
    const float* xi = (const float*)d_in[1];
    const float* Wq = (const float*)d_in[2];
    const float* bq = (const float*)d_in[3];
    const float* Wk = (const float*)d_in[4];
    const float* bk = (const float*)d_in[5];
    const float* Wv = (const float*)d_in[6];
    const float* bv = (const float*)d_in[7];
    const float* Wo = (const float*)d_in[8];
    const float* bo = (const float*)d_in[9];
    float* out = (float*)d_out;

    short* base = (short*)d_ws;
    short* xb   = base;                      // 4096*1024
    short* wqt  = xb  + 4194304;             // 512*1024  } contiguous =>
    short* wkt  = wqt + 524288;              // 512*1024  } wcat[1536][1024]
    short* wvt  = wkt + 524288;              // 512*1024  }
    short* wot  = wvt + 524288;              // 1024*512
    short* spW  = wot + 524288;              // 16*2048*64
    short* sqW  = spW + 2097152;
    short* vtW  = sqW + 2097152;             // [b,h,d,s]
    short* attB = vtW + 2097152;             // 4096*512
    // total = 14,680,064 shorts = 28 MB

    hipLaunchKernelGGL(convert_x, dim3(4096), dim3(256), 0, stream, xr, xi, xb);
    hipLaunchKernelGGL(transpose_w, dim3(32, 32, 4), dim3(256), 0, stream,
                       Wq, Wk, Wv, Wo, wqt, wkt, wvt, wot);
    hipLaunchKernelGGL(qkv_mfma, dim3(24, 32), dim3(128), 0, stream,
                       xb, wqt, bq, bk, bv, spW, sqW, vtW);
    hipLaunchKernelGGL(attn_mfma, dim3(32, 16), dim3(256), 0, stream,
                       spW, sqW, vtW, attB);
    hipLaunchKernelGGL(out_mfma, dim3(16, 32), dim3(256), 0, stream,
                       attB, wot, bo, out);
}

// Round 6
// 184.584 us; speedup vs baseline: 1.0242x; 1.0049x over previous
//
#include <hip/hip_runtime.h>
#include <math.h>

// GeoAttention on gfx950: B=2, S=2048, DIM=512, H=8, HD=64.
// bf16 MFMA (16x16x32) everywhere, fp32 accumulate.
// R14: qkv_mfma + out_mfma rewritten as BARRIER-FREE single-wave blocks.
// R13's counted vmcnt regressed (71us): with 2-wave barrier-coupled blocks
// at 1 wave/SIMD, each K-step serially exposes its latency (~1700cy/step vs
// 80cy MFMA). Fix: 64x64 tile per 64-thread block -> wave-PRIVATE LDS
// (4 A + 4 B chunks = 8 gld_lds16/step), triple-buffered, stage distance 2,
// vmcnt(8) self-sync, NO __syncthreads anywhere. In-order VMEM issue makes
// read-before-overwrite safe. Grid 24x64=1536 (qkv) / 16x64=1024 (out)
// decoupled waves; each wave's loads get 2 full steps to land.
// attn_mfma (R12: packed-f32 poly, u=MFMA(sq,-sp,1), XOR-swizzled LDS)
// and prep kernels unchanged.

typedef __attribute__((ext_vector_type(8))) short short8;
typedef __attribute__((ext_vector_type(4))) short bf16x4;
typedef __attribute__((ext_vector_type(4))) float f32x4;
typedef __attribute__((ext_vector_type(2))) float f32x2;

#define MFMA(a, b, c) __builtin_amdgcn_mfma_f32_16x16x32_bf16((a), (b), (c), 0, 0, 0)

static __device__ __forceinline__ short f2bf(float f) {
    unsigned u = __float_as_uint(f);
    u += 0x7fffu + ((u >> 16) & 1u);          // round-to-nearest-even
    return (short)(u >> 16);
}

// global -> LDS direct DMA, 16B per lane, wave-uniform LDS base + lane*16
static __device__ __forceinline__ void gld_lds16(const short* g, short* l) {
    __builtin_amdgcn_global_load_lds(
        (const __attribute__((address_space(1))) unsigned int*)g,
        (__attribute__((address_space(3))) unsigned int*)l, 16, 0, 0);
}

// ---------------------------------------------------------------------------
// Prep 1: xb[4096][1024] bf16 = concat(x_real, x_imag)
// ---------------------------------------------------------------------------
__global__ __launch_bounds__(256) void convert_x(
    const float* __restrict__ xr, const float* __restrict__ xi,
    short* __restrict__ xb)
{
    int idx = blockIdx.x * 256 + threadIdx.x;
    int e = idx << 2;
    int m = e >> 10, k = e & 1023;
    const float* src = (k < 512) ? xr : xi;
    float4 t = *(const float4*)(src + (size_t)m * 512 + (k & 511));
    unsigned lo = (unsigned short)f2bf(t.x) | ((unsigned)(unsigned short)f2bf(t.y) << 16);
    unsigned hi = (unsigned short)f2bf(t.z) | ((unsigned)(unsigned short)f2bf(t.w) << 16);
    uint2 o; o.x = lo; o.y = hi;
    *(uint2*)(xb + e) = o;
}

// ---------------------------------------------------------------------------
// Prep 2: transpose + convert weights to bf16, n-major [N][K].
// wqt/wkt/wvt are contiguous in the workspace => single wcat[1536][1024].
// ---------------------------------------------------------------------------
__global__ __launch_bounds__(256) void transpose_w(
    const float* __restrict__ Wq, const float* __restrict__ Wk,
    const float* __restrict__ Wv, const float* __restrict__ Wo,
    short* __restrict__ wqt, short* __restrict__ wkt,
    short* __restrict__ wvt, short* __restrict__ wot)
{
    __shared__ float t[32][33];
    const int z = blockIdx.z;
    const float* src = (z == 0) ? Wq : (z == 1) ? Wk : (z == 2) ? Wv : Wo;
    short* dst = (z == 0) ? wqt : (z == 1) ? wkt : (z == 2) ? wvt : wot;
    const int K = (z < 3) ? 1024 : 512;
    const int N = (z < 3) ? 512 : 1024;
    const int n0 = blockIdx.x << 5, k0 = blockIdx.y << 5;
    if (n0 >= N || k0 >= K) return;
    const int tx = threadIdx.x & 31, ty = threadIdx.x >> 5;
    #pragma unroll
    for (int i = 0; i < 4; ++i)
        t[ty + 8 * i][tx] = src[(size_t)(k0 + ty + 8 * i) * N + n0 + tx];
    __syncthreads();
    #pragma unroll
    for (int i = 0; i < 4; ++i)
        dst[(size_t)(n0 + ty + 8 * i) * K + k0 + tx] = f2bf(t[tx][ty + 8 * i]);
}

// ---------------------------------------------------------------------------
// Kernel 1: QKV projection. Grid (24, 64), 64 threads = ONE wave, no barrier.
// Wave-private 64x64 tile over K=1024 (BK=32, 32 steps), triple-buffered
// LDS (8 gld_lds16/stage), stage distance 2, vmcnt(8) self-sync.
// jb: op = jb>>3 (0=Q,1=K,2=V), h = jb&7; tile cols = exactly one head.
// ---------------------------------------------------------------------------
__global__ __launch_bounds__(64) void qkv_mfma(
    const short* __restrict__ xb, const short* __restrict__ wcat,
    const float* __restrict__ bq, const float* __restrict__ bk,
    const float* __restrict__ bv,
    short* __restrict__ sp, short* __restrict__ sq, short* __restrict__ vt)
{
    __shared__ short As[3][64 * 32];      // [row][k] 4KB per buffer
    __shared__ short Bs[3][64 * 32];      // [col][k] 4KB per buffer
    const int jb = blockIdx.x;            // 0..23
    const int m0 = blockIdx.y << 6;       // 64-row tile
    const int lane = threadIdx.x;
    const int l = lane & 15, quad = lane >> 4;

    // staging: 1KB chunk = 16 rows x 64B; lane -> row (lane>>2), seg (lane&3)*8
    const int srow = lane >> 2;
    const int sseg = (lane & 3) << 3;
    const short* gA = xb   + (size_t)(m0        + srow) * 1024 + sseg;
    const short* gB = wcat + (size_t)((jb << 6) + srow) * 1024 + sseg;

    auto STAGE = [&](int bb, int kk) {
        const int k0 = kk << 5;
        #pragma unroll
        for (int t = 0; t < 4; ++t) {
            gld_lds16(gA + k0 + t * 16 * 1024, &As[bb][t << 9]);
            gld_lds16(gB + k0 + t * 16 * 1024, &Bs[bb][t << 9]);
        }
    };

    // prologue: stage k-tiles 0,1 into buffers 0,1; wait buf0 only
    STAGE(0, 0);
    STAGE(1, 1);
    asm volatile("s_waitcnt vmcnt(8)" ::: "memory");

    const f32x4 z4 = {0.f, 0.f, 0.f, 0.f};
    f32x4 acc[4][4];
    #pragma unroll
    for (int i = 0; i < 4; ++i)
        #pragma unroll
        for (int j = 0; j < 4; ++j) acc[i][j] = z4;

    int cb = 0, sb = 2;
    #pragma unroll 1
    for (int kt = 0; kt < 32; ++kt) {
        STAGE(sb, (kt + 2) & 31);         // wrap re-stage at kt=30,31: harmless
        const short* Al = &As[cb][0];
        const short* Bl = &Bs[cb][0];
        short8 af[4], bfr[4];
        #pragma unroll
        for (int i = 0; i < 4; ++i)
            af[i] = *(const short8*)(Al + (((i << 4) + l) << 5) + (quad << 3));
        #pragma unroll
        for (int j = 0; j < 4; ++j)
            bfr[j] = *(const short8*)(Bl + (((j << 4) + l) << 5) + (quad << 3));
        #pragma unroll
        for (int i = 0; i < 4; ++i)
            #pragma unroll
            for (int j = 0; j < 4; ++j)
                acc[i][j] = MFMA(af[i], bfr[j], acc[i][j]);
        // wait: drains the stage issued LAST iteration (buffer needed next
        // step); this iteration's 8 loads stay in flight. In-order VMEM
        // issue + lgkmcnt-before-MFMA make the overwrite race-free.
        asm volatile("s_waitcnt vmcnt(8)" ::: "memory");
        cb = (cb == 2) ? 0 : cb + 1;
        sb = (sb == 2) ? 0 : sb + 1;
    }

    const int op = jb >> 3;               // 0=Q 1=K 2=V
    const int h  = jb & 7;                // head for this block

    if (op < 2) {
        short* dst = (op == 0) ? sp : sq;
        const float* bias = (op == 0) ? bq : bk;
        float bcol[4];
        #pragma unroll
        for (int nt = 0; nt < 4; ++nt) bcol[nt] = bias[(h << 6) + (nt << 4) + l];
        #pragma unroll
        for (int i = 0; i < 4; ++i) {
            #pragma unroll
            for (int reg = 0; reg < 4; ++reg) {
                const int r = m0 + (i << 4) + (quad << 2) + reg;
                const int b = r >> 11, s = r & 2047;
                float v[4];
                #pragma unroll
                for (int nt = 0; nt < 4; ++nt) v[nt] = acc[i][nt][reg] + bcol[nt];
                float mx = fmaxf(fmaxf(v[0], v[1]), fmaxf(v[2], v[3]));
                #pragma unroll
                for (int msk = 1; msk < 16; msk <<= 1) mx = fmaxf(mx, __shfl_xor(mx, msk));
                float e[4], ssum = 0.f;
                #pragma unroll
                for (int nt = 0; nt < 4; ++nt) { e[nt] = __expf(v[nt] - mx); ssum += e[nt]; }
                #pragma unroll
                for (int msk = 1; msk < 16; msk <<= 1) ssum += __shfl_xor(ssum, msk);
                float inv = 1.0f / ssum;
                short* o = dst + ((size_t)((b << 3) + h) * 2048 + s) * 64 + l;
                #pragma unroll
                for (int nt = 0; nt < 4; ++nt)
                    o[nt << 4] = f2bf(sqrtf(e[nt] * inv));
            }
        }
    } else {
        // V: store transposed directly, vt[b,h,d,s]; lane owns 4 consecutive s
        float bcol[4];
        #pragma unroll
        for (int nt = 0; nt < 4; ++nt) bcol[nt] = bv[(h << 6) + (nt << 4) + l];
        #pragma unroll
        for (int i = 0; i < 4; ++i) {
            const int sb2 = m0 + (i << 4) + (quad << 2);
            const int b = sb2 >> 11, s = sb2 & 2047;
            #pragma unroll
            for (int nt = 0; nt < 4; ++nt) {
                const int d = (nt << 4) + l;
                bf16x4 pk;
                #pragma unroll
                for (int reg = 0; reg < 4; ++reg)
                    pk[reg] = f2bf(acc[i][nt][reg] + bcol[nt]);
                *(bf16x4*)(vt + ((size_t)((b << 3) + h) * 64 + d) * 2048 + s) = pk;
            }
        }
    }
}

// ---------------------------------------------------------------------------
// Kernel 2: attention. Grid (32, 16), 256 threads = 4 waves. (unchanged R12)
// LDS tiles stride 64 shorts (128B rows, 8x16B slots), slot s of row r at
// (s ^ (r&7)). QK: u = MFMA(sq, -sp, ones) = 1-bc; poly+den packed f32x2.
// ---------------------------------------------------------------------------
__global__ __launch_bounds__(256, 4) void attn_mfma(
    const short* __restrict__ sp, const short* __restrict__ sq,
    const short* __restrict__ vt, short* __restrict__ attB)
{
    __shared__ __align__(16) short sqT[2][64 * 64];   // [j][d] swizzled
    __shared__ __align__(16) short vtT[2][64 * 64];   // [d][j] swizzled
    __shared__ __align__(16) short Pb[4][16 * 64];    // per-wave P, swizzled
    __shared__ float denB[4][16];
    const int bh = blockIdx.y;
    const int m0 = blockIdx.x << 6;
    const int tid = threadIdx.x;
    const int w = tid >> 6, lane = tid & 63;
    const int l = lane & 15, quad = lane >> 4;
    const int l7 = l & 7;

    const short* spB = sp + (size_t)bh * 2048 * 64;
    const short* sqB = sq + (size_t)bh * 2048 * 64;
    const short* vtB = vt + (size_t)bh * 64 * 2048;

    // persistent sp frags (B-operand): lane l holds sp row (m0+w*16+l).
    // negate once (bf16 sign flip) so MFMA(sq, -sp, 1) = 1 - bc = u.
    const short* apr = spB + (size_t)(m0 + w * 16 + l) * 64 + quad * 8;
    short8 aq0 = *(const short8*)(apr);
    short8 aq1 = *(const short8*)(apr + 32);
    short8 nq0 = aq0 ^ (short)0x8000;
    short8 nq1 = aq1 ^ (short)0x8000;

    // staging: thread -> tile row (tid>>2), 32B chunk (tid&3); swizzled dest
    const int srow = tid >> 2;
    const int scol = (tid & 3) * 16;
    const short* sqG = sqB + (size_t)srow * 64 + scol;   // + j0*64 per jt
    const short* vtG = vtB + (size_t)srow * 2048 + scol; // + j0 per jt
    const int sl0 = (tid & 3) << 1;                      // 16B slot base
    const int sw0 = srow * 64 + (((sl0    ) ^ (srow & 7)) << 3);
    const int sw1 = srow * 64 + (((sl0 | 1) ^ (srow & 7)) << 3);

    // reader slot offset: rows read are (16*k + l) so row&7 == l7 everywhere
    const int sRd = (quad ^ l7) << 3;     // slot quad; ^32 gives slot quad+4

    // prologue: stage jt=0 into buffer 0
    {
        short8 a0 = *(const short8*)(sqG);
        short8 a1 = *(const short8*)(sqG + 8);
        short8 b0 = *(const short8*)(vtG);
        short8 b1 = *(const short8*)(vtG + 8);
        *(short8*)(&sqT[0][sw0]) = a0;
        *(short8*)(&sqT[0][sw1]) = a1;
        *(short8*)(&vtT[0][sw0]) = b0;
        *(short8*)(&vtT[0][sw1]) = b1;
    }
    __syncthreads();

    const f32x4 z4 = {0.f, 0.f, 0.f, 0.f};
    const f32x4 ones4 = {1.f, 1.f, 1.f, 1.f};
    f32x4 acc[4] = {z4, z4, z4, z4};
    f32x2 den2 = {0.f, 0.f};
    short* Pw = &Pb[w][0];

    #pragma unroll 1
    for (int jt = 0; jt < 32; ++jt) {
        const int cb = jt & 1, nb = cb ^ 1;
        const int j0n = ((jt + 1) & 31) << 6;   // wrap: harmless re-stage
        // global loads for jt+1 (latency covered by compute below)
        short8 na0 = *(const short8*)(sqG + (size_t)j0n * 64);
        short8 na1 = *(const short8*)(sqG + (size_t)j0n * 64 + 8);
        short8 nb0 = *(const short8*)(vtG + j0n);
        short8 nb1 = *(const short8*)(vtG + j0n + 8);

        // QK^T transposed: lane l = Q-row, quad*4+reg = j-local; u = 1-bc
        const short* sqL = &sqT[cb][0];
        #pragma unroll
        for (int nt = 0; nt < 4; ++nt) {
            const short* ar = sqL + ((nt * 16 + l) << 6);
            short8 sa0 = *(const short8*)(ar + sRd);
            short8 sa1 = *(const short8*)(ar + (sRd ^ 32));
            f32x4 p = MFMA(sa0, nq0, ones4);
            p = MFMA(sa1, nq1, p);
            // acos(1-u)^2 = u * poly(u); packed f32x2 math (v_pk_fma_f32)
            f32x2 u01 = {p[0], p[1]};
            f32x2 u23 = {p[2], p[3]};
            const f32x2 zz = {0.f, 0.f};
#if __has_builtin(__builtin_elementwise_max)
            u01 = __builtin_elementwise_max(u01, zz);
            u23 = __builtin_elementwise_max(u23, zz);
#else
            u01.x = fmaxf(u01.x, 0.f); u01.y = fmaxf(u01.y, 0.f);
            u23.x = fmaxf(u23.x, 0.f); u23.y = fmaxf(u23.y, 0.f);
#endif
            f32x2 t01 = {0.000922f, 0.000922f};
            f32x2 t23 = t01;
            t01 = t01 * u01 + 0.00152228f;  t23 = t23 * u23 + 0.00152228f;
            t01 = t01 * u01 + 0.00384801f;  t23 = t23 * u23 + 0.00384801f;
            t01 = t01 * u01 + 0.01015873f;  t23 = t23 * u23 + 0.01015873f;
            t01 = t01 * u01 + 0.02857143f;  t23 = t23 * u23 + 0.02857143f;
            t01 = t01 * u01 + 0.08888889f;  t23 = t23 * u23 + 0.08888889f;
            t01 = t01 * u01 + 0.33333333f;  t23 = t23 * u23 + 0.33333333f;
            t01 = t01 * u01 + 2.0f;         t23 = t23 * u23 + 2.0f;
            f32x2 w01 = u01 * t01;
            f32x2 w23 = u23 * t23;
            float e0 = __expf(-w01.x), e1 = __expf(-w01.y);
            float e2 = __expf(-w23.x), e3 = __expf(-w23.y);
            f32x2 es = {e0 + e2, e1 + e3};
            den2 += es;
            // pack 4 consecutive-j bf16 (trunc; bias cancels in num/den)
            uint2 pk;
            pk.x = (__float_as_uint(e0) >> 16) | (__float_as_uint(e1) & 0xffff0000u);
            pk.y = (__float_as_uint(e2) >> 16) | (__float_as_uint(e3) & 0xffff0000u);
            // P row l, logical bytes 32*nt+8*quad -> swizzled slot
            *(uint2*)(&Pw[(l << 6) + ((((nt << 1) + (quad >> 1)) ^ l7) << 3)
                          + ((quad & 1) << 2)]) = pk;
        }

        // PV: P rows as A-frags, V B-frags from LDS (all swizzled reads)
        const short* pr = Pw + (l << 6);
        short8 pa0 = *(const short8*)(pr + sRd);
        short8 pa1 = *(const short8*)(pr + (sRd ^ 32));
        const short* vL = &vtT[cb][0];
        #pragma unroll
        for (int t4 = 0; t4 < 4; ++t4) {
            const short* vr = vL + ((t4 * 16 + l) << 6);
            short8 vb0 = *(const short8*)(vr + sRd);
            short8 vb1 = *(const short8*)(vr + (sRd ^ 32));
            acc[t4] = MFMA(pa0, vb0, acc[t4]);
            acc[t4] = MFMA(pa1, vb1, acc[t4]);
        }

        // write next tiles into the other buffer, then single barrier
        *(short8*)(&sqT[nb][sw0]) = na0;
        *(short8*)(&sqT[nb][sw1]) = na1;
        *(short8*)(&vtT[nb][sw0]) = nb0;
        *(short8*)(&vtT[nb][sw1]) = nb1;
        __syncthreads();
    }

    // den: each quad covered different j -> sum across quads (lane row = l)
    float den = den2.x + den2.y;
    den += __shfl_xor(den, 16);
    den += __shfl_xor(den, 32);
    if (lane < 16) denB[w][l] = den;
    // wave-synchronous LDS: compiler inserts lgkmcnt wait
    float invd[4];
    #pragma unroll
    for (int reg = 0; reg < 4; ++reg)
        invd[reg] = 1.0f / denB[w][quad * 4 + reg];

    const int b = bh >> 3, hh = bh & 7;
    #pragma unroll
    for (int t4 = 0; t4 < 4; ++t4)
        #pragma unroll
        for (int reg = 0; reg < 4; ++reg) {
            const int row = m0 + w * 16 + quad * 4 + reg;
            attB[((size_t)(b * 2048 + row)) * 512 + hh * 64 + t4 * 16 + l] =
                f2bf(acc[t4][reg] * invd[reg]);
        }
}

// ---------------------------------------------------------------------------
// Kernel 3: out = attB[4096][512](bf16) @ Wo + bo -> fp32.
// R14: barrier-free single-wave blocks, grid (16, 64), 64 threads.
// Wave-private 64x64 tile, K=512 (16 steps), triple-buffer, vmcnt(8).
// ---------------------------------------------------------------------------
__global__ __launch_bounds__(64) void out_mfma(
    const short* __restrict__ attB, const short* __restrict__ wot,
    const float* __restrict__ bo, float* __restrict__ out)
{
    __shared__ short As[3][64 * 32];      // 4KB per buffer
    __shared__ short Bs[3][64 * 32];      // 4KB per buffer
    const int n0 = blockIdx.x << 6;       // 64-col tile
    const int m0 = blockIdx.y << 6;       // 64-row tile
    const int lane = threadIdx.x;
    const int l = lane & 15, quad = lane >> 4;

    const int srow = lane >> 2;
    const int sseg = (lane & 3) << 3;
    const short* gA = attB + (size_t)(m0 + srow) * 512 + sseg;
    const short* gB = wot  + (size_t)(n0 + srow) * 512 + sseg;

    auto STAGE = [&](int bb, int kk) {
        const int k0 = kk << 5;
        #pragma unroll
        for (int t = 0; t < 4; ++t) {
            gld_lds16(gA + k0 + t * 16 * 512, &As[bb][t << 9]);
            gld_lds16(gB + k0 + t * 16 * 512, &Bs[bb][t << 9]);
        }
    };

    STAGE(0, 0);
    STAGE(1, 1);
    asm volatile("s_waitcnt vmcnt(8)" ::: "memory");

    const f32x4 z4 = {0.f, 0.f, 0.f, 0.f};
    f32x4 acc[4][4];
    #pragma unroll
    for (int i = 0; i < 4; ++i)
        #pragma unroll
        for (int j = 0; j < 4; ++j) acc[i][j] = z4;

    int cb = 0, sb = 2;
    #pragma unroll 1
    for (int kt = 0; kt < 16; ++kt) {
        STAGE(sb, (kt + 2) & 15);         // wrap re-stage at kt=14,15: harmless
        const short* Al = &As[cb][0];
        const short* Bl = &Bs[cb][0];
        short8 af[4], bfr[4];
        #pragma unroll
        for (int i = 0; i < 4; ++i)
            af[i] = *(const short8*)(Al + (((i << 4) + l) << 5) + (quad << 3));
        #pragma unroll
        for (int j = 0; j < 4; ++j)
            bfr[j] = *(const short8*)(Bl + (((j << 4) + l) << 5) + (quad << 3));
        #pragma unroll
        for (int i = 0; i < 4; ++i)
            #pragma unroll
            for (int j = 0; j < 4; ++j)
                acc[i][j] = MFMA(af[i], bfr[j], acc[i][j]);
        asm volatile("s_waitcnt vmcnt(8)" ::: "memory");
        cb = (cb == 2) ? 0 : cb + 1;
        sb = (sb == 2) ? 0 : sb + 1;
    }

    float bcol[4];
    #pragma unroll
    for (int nt = 0; nt < 4; ++nt) bcol[nt] = bo[n0 + (nt << 4) + l];
    #pragma unroll
    for (int i = 0; i < 4; ++i)
        #pragma unroll
        for (int reg = 0; reg < 4; ++reg) {
            const int m = m0 + (i << 4) + (quad << 2) + reg;
            float* o = out + (size_t)m * 1024 + n0 + l;
            #pragma unroll
            for (int nt = 0; nt < 4; ++nt)
                o[nt << 4] = acc[i][nt][reg] + bcol[nt];
        }
}

// ---------------------------------------------------------------------------
extern "C" void kernel_launch(void* const* d_in, const int* in_sizes, int n_in,
                              void* d_out, int out_size, void* d_ws, size_t ws_size,
                              hipStream_t stream) {
    const float* xr = (const float*)d_in[0];
    const float* xi = (const float*)d_in[1];
    const float* Wq = (const float*)d_in[2];
    const float* bq = (const float*)d_in[3];
    const float* Wk = (const float*)d_in[4];
    const float* bk = (const float*)d_in[5];
    const float* Wv = (const float*)d_in[6];
    const float* bv = (const float*)d_in[7];
    const float* Wo = (const float*)d_in[8];
    const float* bo = (const float*)d_in[9];
    float* out = (float*)d_out;

    short* base = (short*)d_ws;
    short* xb   = base;                      // 4096*1024
    short* wqt  = xb  + 4194304;             // 512*1024  } contiguous =>
    short* wkt  = wqt + 524288;              // 512*1024  } wcat[1536][1024]
    short* wvt  = wkt + 524288;              // 512*1024  }
    short* wot  = wvt + 524288;              // 1024*512
    short* spW  = wot + 524288;              // 16*2048*64
    short* sqW  = spW + 2097152;
    short* vtW  = sqW + 2097152;             // [b,h,d,s]
    short* attB = vtW + 2097152;             // 4096*512
    // total = 14,680,064 shorts = 28 MB

    hipLaunchKernelGGL(convert_x, dim3(4096), dim3(256), 0, stream, xr, xi, xb);
    hipLaunchKernelGGL(transpose_w, dim3(32, 32, 4), dim3(256), 0, stream,
                       Wq, Wk, Wv, Wo, wqt, wkt, wvt, wot);
    hipLaunchKernelGGL(qkv_mfma, dim3(24, 64), dim3(64), 0, stream,
                       xb, wqt, bq, bk, bv, spW, sqW, vtW);
    hipLaunchKernelGGL(attn_mfma, dim3(32, 16), dim3(256), 0, stream,
                       spW, sqW, vtW, attB);
    hipLaunchKernelGGL(out_mfma, dim3(16, 64), dim3(64), 0, stream,
                       attB, wot, bo, out);
}

// Round 7
// 180.177 us; speedup vs baseline: 1.0493x; 1.0245x over previous
//
#include <hip/hip_runtime.h>
#include <math.h>

// GeoAttention on gfx950: B=2, S=2048, DIM=512, H=8, HD=64.
// bf16 MFMA (16x16x32) everywhere, fp32 accumulate.
// R15: attn_mfma restructured for occupancy + LDS traffic:
//  (1) P-in-registers: QK's packed pk[nt] (lane=Q-row, j=16nt+4q+reg) is used
//      DIRECTLY as the PV A-fragment; the matching j-permutation
//      pi(8q+e)=16*(e>=4)+4q+(e&3) is folded into the vtT STAGING slots
//      (4x ds_write_b64, same XOR swizzle; read side unchanged). Pb LDS,
//      its 4 writes + 2 reads per lane per jt, and the lgkm write->read
//      serial chain are all deleted. LDS 41.5 -> 32 KB.
//  (2) j-split x2 via blockIdx.z: grid (32,16,2)=1024 blocks -> 4 blocks/CU
//      (was 2), each sweeping 16 jt; partial num (f32) + den written to ws;
//      new combine_attn kernel does (n0+n1)/(d0+d1) -> attB bf16.
//  (3) poly coefficients pre-multiplied by -log2(e); e = exp2(w) via
//      __builtin_amdgcn_exp2f — deletes the per-element x log2e mul.
// qkv/out (R14 barrier-free single-wave) and preps unchanged.

typedef __attribute__((ext_vector_type(8))) short short8;
typedef __attribute__((ext_vector_type(4))) short bf16x4;
typedef __attribute__((ext_vector_type(4))) float f32x4;
typedef __attribute__((ext_vector_type(2))) float f32x2;
typedef __attribute__((ext_vector_type(4))) unsigned int u32x4;

#define MFMA(a, b, c) __builtin_amdgcn_mfma_f32_16x16x32_bf16((a), (b), (c), 0, 0, 0)

static __device__ __forceinline__ short f2bf(float f) {
    unsigned u = __float_as_uint(f);
    u += 0x7fffu + ((u >> 16) & 1u);          // round-to-nearest-even
    return (short)(u >> 16);
}

// global -> LDS direct DMA, 16B per lane, wave-uniform LDS base + lane*16
static __device__ __forceinline__ void gld_lds16(const short* g, short* l) {
    __builtin_amdgcn_global_load_lds(
        (const __attribute__((address_space(1))) unsigned int*)g,
        (__attribute__((address_space(3))) unsigned int*)l, 16, 0, 0);
}

// ---------------------------------------------------------------------------
// Prep 1: xb[4096][1024] bf16 = concat(x_real, x_imag)
// ---------------------------------------------------------------------------
__global__ __launch_bounds__(256) void convert_x(
    const float* __restrict__ xr, const float* __restrict__ xi,
    short* __restrict__ xb)
{
    int idx = blockIdx.x * 256 + threadIdx.x;
    int e = idx << 2;
    int m = e >> 10, k = e & 1023;
    const float* src = (k < 512) ? xr : xi;
    float4 t = *(const float4*)(src + (size_t)m * 512 + (k & 511));
    unsigned lo = (unsigned short)f2bf(t.x) | ((unsigned)(unsigned short)f2bf(t.y) << 16);
    unsigned hi = (unsigned short)f2bf(t.z) | ((unsigned)(unsigned short)f2bf(t.w) << 16);
    uint2 o; o.x = lo; o.y = hi;
    *(uint2*)(xb + e) = o;
}

// ---------------------------------------------------------------------------
// Prep 2: transpose + convert weights to bf16, n-major [N][K].
// wqt/wkt/wvt are contiguous in the workspace => single wcat[1536][1024].
// ---------------------------------------------------------------------------
__global__ __launch_bounds__(256) void transpose_w(
    const float* __restrict__ Wq, const float* __restrict__ Wk,
    const float* __restrict__ Wv, const float* __restrict__ Wo,
    short* __restrict__ wqt, short* __restrict__ wkt,
    short* __restrict__ wvt, short* __restrict__ wot)
{
    __shared__ float t[32][33];
    const int z = blockIdx.z;
    const float* src = (z == 0) ? Wq : (z == 1) ? Wk : (z == 2) ? Wv : Wo;
    short* dst = (z == 0) ? wqt : (z == 1) ? wkt : (z == 2) ? wvt : wot;
    const int K = (z < 3) ? 1024 : 512;
    const int N = (z < 3) ? 512 : 1024;
    const int n0 = blockIdx.x << 5, k0 = blockIdx.y << 5;
    if (n0 >= N || k0 >= K) return;
    const int tx = threadIdx.x & 31, ty = threadIdx.x >> 5;
    #pragma unroll
    for (int i = 0; i < 4; ++i)
        t[ty + 8 * i][tx] = src[(size_t)(k0 + ty + 8 * i) * N + n0 + tx];
    __syncthreads();
    #pragma unroll
    for (int i = 0; i < 4; ++i)
        dst[(size_t)(n0 + ty + 8 * i) * K + k0 + tx] = f2bf(t[tx][ty + 8 * i]);
}

// ---------------------------------------------------------------------------
// Kernel 1: QKV projection. Grid (24, 64), 64 threads = ONE wave, no barrier.
// (unchanged R14) Wave-private 64x64 tile, K=1024 (32 steps), triple-buffer,
// vmcnt(8) self-sync. jb: op = jb>>3, h = jb&7.
// ---------------------------------------------------------------------------
__global__ __launch_bounds__(64) void qkv_mfma(
    const short* __restrict__ xb, const short* __restrict__ wcat,
    const float* __restrict__ bq, const float* __restrict__ bk,
    const float* __restrict__ bv,
    short* __restrict__ sp, short* __restrict__ sq, short* __restrict__ vt)
{
    __shared__ short As[3][64 * 32];      // [row][k] 4KB per buffer
    __shared__ short Bs[3][64 * 32];      // [col][k] 4KB per buffer
    const int jb = blockIdx.x;            // 0..23
    const int m0 = blockIdx.y << 6;       // 64-row tile
    const int lane = threadIdx.x;
    const int l = lane & 15, quad = lane >> 4;

    const int srow = lane >> 2;
    const int sseg = (lane & 3) << 3;
    const short* gA = xb   + (size_t)(m0        + srow) * 1024 + sseg;
    const short* gB = wcat + (size_t)((jb << 6) + srow) * 1024 + sseg;

    auto STAGE = [&](int bb, int kk) {
        const int k0 = kk << 5;
        #pragma unroll
        for (int t = 0; t < 4; ++t) {
            gld_lds16(gA + k0 + t * 16 * 1024, &As[bb][t << 9]);
            gld_lds16(gB + k0 + t * 16 * 1024, &Bs[bb][t << 9]);
        }
    };

    STAGE(0, 0);
    STAGE(1, 1);
    asm volatile("s_waitcnt vmcnt(8)" ::: "memory");

    const f32x4 z4 = {0.f, 0.f, 0.f, 0.f};
    f32x4 acc[4][4];
    #pragma unroll
    for (int i = 0; i < 4; ++i)
        #pragma unroll
        for (int j = 0; j < 4; ++j) acc[i][j] = z4;

    int cb = 0, sb = 2;
    #pragma unroll 1
    for (int kt = 0; kt < 32; ++kt) {
        STAGE(sb, (kt + 2) & 31);         // wrap re-stage at kt=30,31: harmless
        const short* Al = &As[cb][0];
        const short* Bl = &Bs[cb][0];
        short8 af[4], bfr[4];
        #pragma unroll
        for (int i = 0; i < 4; ++i)
            af[i] = *(const short8*)(Al + (((i << 4) + l) << 5) + (quad << 3));
        #pragma unroll
        for (int j = 0; j < 4; ++j)
            bfr[j] = *(const short8*)(Bl + (((j << 4) + l) << 5) + (quad << 3));
        #pragma unroll
        for (int i = 0; i < 4; ++i)
            #pragma unroll
            for (int j = 0; j < 4; ++j)
                acc[i][j] = MFMA(af[i], bfr[j], acc[i][j]);
        asm volatile("s_waitcnt vmcnt(8)" ::: "memory");
        cb = (cb == 2) ? 0 : cb + 1;
        sb = (sb == 2) ? 0 : sb + 1;
    }

    const int op = jb >> 3;               // 0=Q 1=K 2=V
    const int h  = jb & 7;                // head for this block

    if (op < 2) {
        short* dst = (op == 0) ? sp : sq;
        const float* bias = (op == 0) ? bq : bk;
        float bcol[4];
        #pragma unroll
        for (int nt = 0; nt < 4; ++nt) bcol[nt] = bias[(h << 6) + (nt << 4) + l];
        #pragma unroll
        for (int i = 0; i < 4; ++i) {
            #pragma unroll
            for (int reg = 0; reg < 4; ++reg) {
                const int r = m0 + (i << 4) + (quad << 2) + reg;
                const int b = r >> 11, s = r & 2047;
                float v[4];
                #pragma unroll
                for (int nt = 0; nt < 4; ++nt) v[nt] = acc[i][nt][reg] + bcol[nt];
                float mx = fmaxf(fmaxf(v[0], v[1]), fmaxf(v[2], v[3]));
                #pragma unroll
                for (int msk = 1; msk < 16; msk <<= 1) mx = fmaxf(mx, __shfl_xor(mx, msk));
                float e[4], ssum = 0.f;
                #pragma unroll
                for (int nt = 0; nt < 4; ++nt) { e[nt] = __expf(v[nt] - mx); ssum += e[nt]; }
                #pragma unroll
                for (int msk = 1; msk < 16; msk <<= 1) ssum += __shfl_xor(ssum, msk);
                float inv = 1.0f / ssum;
                short* o = dst + ((size_t)((b << 3) + h) * 2048 + s) * 64 + l;
                #pragma unroll
                for (int nt = 0; nt < 4; ++nt)
                    o[nt << 4] = f2bf(sqrtf(e[nt] * inv));
            }
        }
    } else {
        float bcol[4];
        #pragma unroll
        for (int nt = 0; nt < 4; ++nt) bcol[nt] = bv[(h << 6) + (nt << 4) + l];
        #pragma unroll
        for (int i = 0; i < 4; ++i) {
            const int sb2 = m0 + (i << 4) + (quad << 2);
            const int b = sb2 >> 11, s = sb2 & 2047;
            #pragma unroll
            for (int nt = 0; nt < 4; ++nt) {
                const int d = (nt << 4) + l;
                bf16x4 pk;
                #pragma unroll
                for (int reg = 0; reg < 4; ++reg)
                    pk[reg] = f2bf(acc[i][nt][reg] + bcol[nt]);
                *(bf16x4*)(vt + ((size_t)((b << 3) + h) * 64 + d) * 2048 + s) = pk;
            }
        }
    }
}

// ---------------------------------------------------------------------------
// Kernel 2: attention partials. Grid (32, 16, 2), 256 threads = 4 waves.
// z = j-half (16 jt each). sqT XOR-swizzled as before. vtT staged with the
// pi-permuted column order so QK's packed pk[nt] registers ARE the PV
// A-fragments (no P LDS). Outputs: pnum f32 (no division), pden per row.
// ---------------------------------------------------------------------------
__global__ __launch_bounds__(256, 4) void attn_mfma(
    const short* __restrict__ sp, const short* __restrict__ sq,
    const short* __restrict__ vt,
    float* __restrict__ pnum, float* __restrict__ pden)
{
    __shared__ __align__(16) short sqT[2][64 * 64];   // [j][d] swizzled
    __shared__ __align__(16) short vtT[2][64 * 64];   // [d][pi(j)] swizzled
    const int bh = blockIdx.y;
    const int m0 = blockIdx.x << 6;
    const int z  = blockIdx.z;            // j-half: jt in [16z, 16z+16)
    const int tid = threadIdx.x;
    const int w = tid >> 6, lane = tid & 63;
    const int l = lane & 15, quad = lane >> 4;
    const int l7 = l & 7;

    const short* spB = sp + (size_t)bh * 2048 * 64;
    const short* sqB = sq + (size_t)bh * 2048 * 64;
    const short* vtB = vt + (size_t)bh * 64 * 2048;

    // persistent sp frags (B-operand), negated: MFMA(sq,-sp,1) = 1-bc = u
    const short* apr = spB + (size_t)(m0 + w * 16 + l) * 64 + quad * 8;
    short8 nq0 = (*(const short8*)(apr)) ^ (short)0x8000;
    short8 nq1 = (*(const short8*)(apr + 32)) ^ (short)0x8000;

    // staging: thread -> tile row (tid>>2), 32B col chunk (tid&3)
    const int srow = tid >> 2;
    const int t3 = tid & 3;
    const int scol = t3 * 16;
    const short* sqG = sqB + (size_t)srow * 64 + scol;   // + j0*64 per jt
    const short* vtG = vtB + (size_t)srow * 2048 + scol; // + j0 per jt
    // sq staging (unchanged): 2x b128 at XOR-swizzled 16B slots
    const int sl0 = t3 << 1;
    const int sw0 = srow * 64 + (((sl0    ) ^ (srow & 7)) << 3);
    const int sw1 = srow * 64 + (((sl0 | 1) ^ (srow & 7)) << 3);
    // vt staging: 4x b64 at pi-permuted, XOR-swizzled slots.
    // chunk m holds cols j = 32*(t3>>1) + 16*(t3&1) + 4*mq + r mapped to
    // slot 32*(t3>>1) + 8*m + 4*(t3&1); 16B unit = 4*(t3>>1)+m, half = t3&1.
    int vwo[4];
    #pragma unroll
    for (int m = 0; m < 4; ++m)
        vwo[m] = srow * 64 + ((((t3 >> 1) * 4 + m) ^ (srow & 7)) << 3)
               + ((t3 & 1) << 2);

    // reader slot offset: rows read are (16*k + l) so row&7 == l7 everywhere
    const int sRd = (quad ^ l7) << 3;     // 16B-slot quad; ^32 -> slot quad+4

    // prologue: stage jt = 16z into buffer 0
    {
        const int j0 = (z << 4) << 6;
        short8 a0 = *(const short8*)(sqG + (size_t)j0 * 64);
        short8 a1 = *(const short8*)(sqG + (size_t)j0 * 64 + 8);
        short8 b0 = *(const short8*)(vtG + j0);
        short8 b1 = *(const short8*)(vtG + j0 + 8);
        *(short8*)(&sqT[0][sw0]) = a0;
        *(short8*)(&sqT[0][sw1]) = a1;
        u32x4 u0 = __builtin_bit_cast(u32x4, b0);
        u32x4 u1 = __builtin_bit_cast(u32x4, b1);
        *(uint2*)(&vtT[0][vwo[0]]) = (uint2){u0.x, u0.y};
        *(uint2*)(&vtT[0][vwo[1]]) = (uint2){u0.z, u0.w};
        *(uint2*)(&vtT[0][vwo[2]]) = (uint2){u1.x, u1.y};
        *(uint2*)(&vtT[0][vwo[3]]) = (uint2){u1.z, u1.w};
    }
    __syncthreads();

    const f32x4 ones4 = {1.f, 1.f, 1.f, 1.f};
    const f32x4 z4 = {0.f, 0.f, 0.f, 0.f};
    f32x4 acc[4] = {z4, z4, z4, z4};
    f32x2 den2 = {0.f, 0.f};

    #pragma unroll 1
    for (int jtl = 0; jtl < 16; ++jtl) {
        const int cb = jtl & 1, nb = cb ^ 1;
        const int j0n = ((z << 4) + ((jtl + 1) & 15)) << 6;  // wrap: harmless
        short8 na0 = *(const short8*)(sqG + (size_t)j0n * 64);
        short8 na1 = *(const short8*)(sqG + (size_t)j0n * 64 + 8);
        short8 nb0 = *(const short8*)(vtG + j0n);
        short8 nb1 = *(const short8*)(vtG + j0n + 8);

        // QK^T transposed: lane l = Q-row, 16nt+4q+reg = j-local; u = 1-bc
        uint2 pk[4];
        const short* sqL = &sqT[cb][0];
        #pragma unroll
        for (int nt = 0; nt < 4; ++nt) {
            const short* ar = sqL + ((nt * 16 + l) << 6);
            short8 sa0 = *(const short8*)(ar + sRd);
            short8 sa1 = *(const short8*)(ar + (sRd ^ 32));
            f32x4 p = MFMA(sa0, nq0, ones4);
            p = MFMA(sa1, nq1, p);
            // w = u * poly(u), coefficients pre-scaled by -log2(e);
            // e = exp2(w). packed f32x2 math (v_pk_fma_f32).
            f32x2 u01 = {p[0], p[1]};
            f32x2 u23 = {p[2], p[3]};
            const f32x2 zz = {0.f, 0.f};
#if __has_builtin(__builtin_elementwise_max)
            u01 = __builtin_elementwise_max(u01, zz);
            u23 = __builtin_elementwise_max(u23, zz);
#else
            u01.x = fmaxf(u01.x, 0.f); u01.y = fmaxf(u01.y, 0.f);
            u23.x = fmaxf(u23.x, 0.f); u23.y = fmaxf(u23.y, 0.f);
#endif
            f32x2 t01 = {-0.00133017f, -0.00133017f};
            f32x2 t23 = t01;
            t01 = t01 * u01 - 0.00219618f;  t23 = t23 * u23 - 0.00219618f;
            t01 = t01 * u01 - 0.00555151f;  t23 = t23 * u23 - 0.00555151f;
            t01 = t01 * u01 - 0.01465597f;  t23 = t23 * u23 - 0.01465597f;
            t01 = t01 * u01 - 0.04121986f;  t23 = t23 * u23 - 0.04121986f;
            t01 = t01 * u01 - 0.12823956f;  t23 = t23 * u23 - 0.12823956f;
            t01 = t01 * u01 - 0.48089834f;  t23 = t23 * u23 - 0.48089834f;
            t01 = t01 * u01 - 2.88539008f;  t23 = t23 * u23 - 2.88539008f;
            f32x2 w01 = u01 * t01;          // <= 0
            f32x2 w23 = u23 * t23;
#if __has_builtin(__builtin_amdgcn_exp2f)
            float e0 = __builtin_amdgcn_exp2f(w01.x);
            float e1 = __builtin_amdgcn_exp2f(w01.y);
            float e2 = __builtin_amdgcn_exp2f(w23.x);
            float e3 = __builtin_amdgcn_exp2f(w23.y);
#else
            float e0 = exp2f(w01.x), e1 = exp2f(w01.y);
            float e2 = exp2f(w23.x), e3 = exp2f(w23.y);
#endif
            f32x2 es = {e0 + e2, e1 + e3};
            den2 += es;
            pk[nt].x = (__float_as_uint(e0) >> 16) | (__float_as_uint(e1) & 0xffff0000u);
            pk[nt].y = (__float_as_uint(e2) >> 16) | (__float_as_uint(e3) & 0xffff0000u);
        }

        // PV: pk registers ARE the A-frags (j-order matched by vtT staging)
        u32x4 c0; c0.x = pk[0].x; c0.y = pk[0].y; c0.z = pk[1].x; c0.w = pk[1].y;
        u32x4 c1; c1.x = pk[2].x; c1.y = pk[2].y; c1.z = pk[3].x; c1.w = pk[3].y;
        short8 pa0 = __builtin_bit_cast(short8, c0);
        short8 pa1 = __builtin_bit_cast(short8, c1);
        const short* vL = &vtT[cb][0];
        #pragma unroll
        for (int t4 = 0; t4 < 4; ++t4) {
            const short* vr = vL + ((t4 * 16 + l) << 6);
            short8 vb0 = *(const short8*)(vr + sRd);
            short8 vb1 = *(const short8*)(vr + (sRd ^ 32));
            acc[t4] = MFMA(pa0, vb0, acc[t4]);
            acc[t4] = MFMA(pa1, vb1, acc[t4]);
        }

        // write next tiles into the other buffer, then single barrier
        *(short8*)(&sqT[nb][sw0]) = na0;
        *(short8*)(&sqT[nb][sw1]) = na1;
        u32x4 u0 = __builtin_bit_cast(u32x4, nb0);
        u32x4 u1 = __builtin_bit_cast(u32x4, nb1);
        *(uint2*)(&vtT[nb][vwo[0]]) = (uint2){u0.x, u0.y};
        *(uint2*)(&vtT[nb][vwo[1]]) = (uint2){u0.z, u0.w};
        *(uint2*)(&vtT[nb][vwo[2]]) = (uint2){u1.x, u1.y};
        *(uint2*)(&vtT[nb][vwo[3]]) = (uint2){u1.z, u1.w};
        __syncthreads();
    }

    // den: sum across quads (each quad covered different j); lane<16 stores
    float den = den2.x + den2.y;
    den += __shfl_xor(den, 16);
    den += __shfl_xor(den, 32);
    if (lane < 16)
        pden[(size_t)z * 32768 + bh * 2048 + m0 + w * 16 + l] = den;

    // partial numerator, f32, no division
    const int b = bh >> 3, hh = bh & 7;
    float* np = pnum + (size_t)z * 4096 * 512;
    #pragma unroll
    for (int t4 = 0; t4 < 4; ++t4)
        #pragma unroll
        for (int reg = 0; reg < 4; ++reg) {
            const int row = m0 + w * 16 + quad * 4 + reg;
            np[((size_t)(b * 2048 + row)) * 512 + hh * 64 + t4 * 16 + l] =
                acc[t4][reg];
        }
}

// ---------------------------------------------------------------------------
// Kernel 2b: combine halves -> attB bf16. 2M elems, 8 per thread.
// ---------------------------------------------------------------------------
__global__ __launch_bounds__(256) void combine_attn(
    const float* __restrict__ pnum, const float* __restrict__ pden,
    short* __restrict__ attB)
{
    const int idx = (blockIdx.x * 256 + threadIdx.x) << 3;
    const int r = idx >> 9;               // 0..4095
    const int c = idx & 511;
    const int hh = c >> 6;
    const int bh = ((r >> 11) << 3) + hh;
    const int srow = r & 2047;
    const float d = pden[bh * 2048 + srow] + pden[32768 + bh * 2048 + srow];
    const float inv = 1.0f / d;
    const float* n0 = pnum + (size_t)r * 512 + c;
    const float* n1 = n0 + (size_t)4096 * 512;
    float4 a0 = *(const float4*)(n0);
    float4 a1 = *(const float4*)(n0 + 4);
    float4 b0 = *(const float4*)(n1);
    float4 b1 = *(const float4*)(n1 + 4);
    short8 o;
    o[0] = f2bf((a0.x + b0.x) * inv);
    o[1] = f2bf((a0.y + b0.y) * inv);
    o[2] = f2bf((a0.z + b0.z) * inv);
    o[3] = f2bf((a0.w + b0.w) * inv);
    o[4] = f2bf((a1.x + b1.x) * inv);
    o[5] = f2bf((a1.y + b1.y) * inv);
    o[6] = f2bf((a1.z + b1.z) * inv);
    o[7] = f2bf((a1.w + b1.w) * inv);
    *(short8*)(attB + idx) = o;
}

// ---------------------------------------------------------------------------
// Kernel 3: out = attB[4096][512](bf16) @ Wo + bo -> fp32. (unchanged R14)
// Barrier-free single-wave blocks, grid (16, 64), triple-buffer, vmcnt(8).
// ---------------------------------------------------------------------------
__global__ __launch_bounds__(64) void out_mfma(
    const short* __restrict__ attB, const short* __restrict__ wot,
    const float* __restrict__ bo, float* __restrict__ out)
{
    __shared__ short As[3][64 * 32];      // 4KB per buffer
    __shared__ short Bs[3][64 * 32];      // 4KB per buffer
    const int n0 = blockIdx.x << 6;       // 64-col tile
    const int m0 = blockIdx.y << 6;       // 64-row tile
    const int lane = threadIdx.x;
    const int l = lane & 15, quad = lane >> 4;

    const int srow = lane >> 2;
    const int sseg = (lane & 3) << 3;
    const short* gA = attB + (size_t)(m0 + srow) * 512 + sseg;
    const short* gB = wot  + (size_t)(n0 + srow) * 512 + sseg;

    auto STAGE = [&](int bb, int kk) {
        const int k0 = kk << 5;
        #pragma unroll
        for (int t = 0; t < 4; ++t) {
            gld_lds16(gA + k0 + t * 16 * 512, &As[bb][t << 9]);
            gld_lds16(gB + k0 + t * 16 * 512, &Bs[bb][t << 9]);
        }
    };

    STAGE(0, 0);
    STAGE(1, 1);
    asm volatile("s_waitcnt vmcnt(8)" ::: "memory");

    const f32x4 z4 = {0.f, 0.f, 0.f, 0.f};
    f32x4 acc[4][4];
    #pragma unroll
    for (int i = 0; i < 4; ++i)
        #pragma unroll
        for (int j = 0; j < 4; ++j) acc[i][j] = z4;

    int cb = 0, sb = 2;
    #pragma unroll 1
    for (int kt = 0; kt < 16; ++kt) {
        STAGE(sb, (kt + 2) & 15);         // wrap re-stage at kt=14,15: harmless
        const short* Al = &As[cb][0];
        const short* Bl = &Bs[cb][0];
        short8 af[4], bfr[4];
        #pragma unroll
        for (int i = 0; i < 4; ++i)
            af[i] = *(const short8*)(Al + (((i << 4) + l) << 5) + (quad << 3));
        #pragma unroll
        for (int j = 0; j < 4; ++j)
            bfr[j] = *(const short8*)(Bl + (((j << 4) + l) << 5) + (quad << 3));
        #pragma unroll
        for (int i = 0; i < 4; ++i)
            #pragma unroll
            for (int j = 0; j < 4; ++j)
                acc[i][j] = MFMA(af[i], bfr[j], acc[i][j]);
        asm volatile("s_waitcnt vmcnt(8)" ::: "memory");
        cb = (cb == 2) ? 0 : cb + 1;
        sb = (sb == 2) ? 0 : sb + 1;
    }

    float bcol[4];
    #pragma unroll
    for (int nt = 0; nt < 4; ++nt) bcol[nt] = bo[n0 + (nt << 4) + l];
    #pragma unroll
    for (int i = 0; i < 4; ++i)
        #pragma unroll
        for (int reg = 0; reg < 4; ++reg) {
            const int m = m0 + (i << 4) + (quad << 2) + reg;
            float* o = out + (size_t)m * 1024 + n0 + l;
            #pragma unroll
            for (int nt = 0; nt < 4; ++nt)
                o[nt << 4] = acc[i][nt][reg] + bcol[nt];
        }
}

// ---------------------------------------------------------------------------
extern "C" void kernel_launch(void* const* d_in, const int* in_sizes, int n_in,
                              void* d_out, int out_size, void* d_ws, size_t ws_size,
                              hipStream_t stream) {
    const float* xr = (const float*)d_in[0];
    const float* xi = (const float*)d_in[1];
    const float* Wq = (const float*)d_in[2];
    const float* bq = (const float*)d_in[3];
    const float* Wk = (const float*)d_in[4];
    const float* bk = (const float*)d_in[5];
    const float* Wv = (const float*)d_in[6];
    const float* bv = (const float*)d_in[7];
    const float* Wo = (const float*)d_in[8];
    const float* bo = (const float*)d_in[9];
    float* out = (float*)d_out;

    short* base = (short*)d_ws;
    short* xb   = base;                      // 4096*1024
    short* wqt  = xb  + 4194304;             // 512*1024  } contiguous =>
    short* wkt  = wqt + 524288;              // 512*1024  } wcat[1536][1024]
    short* wvt  = wkt + 524288;              // 512*1024  }
    short* wot  = wvt + 524288;              // 1024*512
    short* spW  = wot + 524288;              // 16*2048*64
    short* sqW  = spW + 2097152;
    short* vtW  = sqW + 2097152;             // [b,h,d,s]
    short* attB = vtW + 2097152;             // 4096*512
    float* pnum = (float*)(attB + 2097152);  // 2 x 4096*512 f32 = 16MB
    float* pden = pnum + 8388608;            // 2 x 16*2048 f32
    // total = 29,360,128 B + 16MB + 256KB ~= 46.4 MB

    hipLaunchKernelGGL(convert_x, dim3(4096), dim3(256), 0, stream, xr, xi, xb);
    hipLaunchKernelGGL(transpose_w, dim3(32, 32, 4), dim3(256), 0, stream,
                       Wq, Wk, Wv, Wo, wqt, wkt, wvt, wot);
    hipLaunchKernelGGL(qkv_mfma, dim3(24, 64), dim3(64), 0, stream,
                       xb, wqt, bq, bk, bv, spW, sqW, vtW);
    hipLaunchKernelGGL(attn_mfma, dim3(32, 16, 2), dim3(256), 0, stream,
                       spW, sqW, vtW, pnum, pden);
    hipLaunchKernelGGL(combine_attn, dim3(1024), dim3(256), 0, stream,
                       pnum, pden, attB);
    hipLaunchKernelGGL(out_mfma, dim3(16, 64), dim3(64), 0, stream,
                       attB, wot, bo, out);
}